// Round 2
// baseline (1054.826 us; speedup 1.0000x reference)
//
#include <hip/hip_runtime.h>
#include <math.h>

// ---------------- common ----------------
typedef __attribute__((ext_vector_type(8))) short bf16x8;
typedef __attribute__((ext_vector_type(4))) float f32x4;

__device__ __forceinline__ unsigned short f2bf(float f) {
  union { float f; unsigned u; } v; v.f = f;
  unsigned r = v.u + 0x7fff + ((v.u >> 16) & 1);
  return (unsigned short)(r >> 16);
}

__device__ __forceinline__ void gll16(const void* g, void* l) {
  __builtin_amdgcn_global_load_lds(
      (const __attribute__((address_space(1))) void*)g,
      (__attribute__((address_space(3))) void*)l, 16, 0, 0);
}

#define BB 4
#define TT 4096
#define CC 1024
#define HH 4096
#define MM 16384   // B*T

// ---------------- LayerNorm (one block per row, C=1024) ----------------
__global__ __launch_bounds__(256) void ln_f32_kernel(
    const float* __restrict__ x, const float* __restrict__ w,
    const float* __restrict__ b, float* __restrict__ out)
{
  size_t row = blockIdx.x;
  const float4* xr = (const float4*)(x + row * CC);
  int tid = threadIdx.x;
  float4 v = xr[tid];
  float s = v.x + v.y + v.z + v.w;
  float sq = v.x*v.x + v.y*v.y + v.z*v.z + v.w*v.w;
  for (int o = 32; o; o >>= 1) { s += __shfl_xor(s, o); sq += __shfl_xor(sq, o); }
  __shared__ float ss[4], ssq[4];
  int wv = tid >> 6, lane = tid & 63;
  if (lane == 0) { ss[wv] = s; ssq[wv] = sq; }
  __syncthreads();
  s = ss[0] + ss[1] + ss[2] + ss[3];
  sq = ssq[0] + ssq[1] + ssq[2] + ssq[3];
  float mu = s * (1.f / CC);
  float var = sq * (1.f / CC) - mu * mu;
  float rstd = rsqrtf(var + 1e-5f);
  float4 wv4 = ((const float4*)w)[tid];
  float4 bv4 = ((const float4*)b)[tid];
  float4 o;
  o.x = (v.x - mu) * rstd * wv4.x + bv4.x;
  o.y = (v.y - mu) * rstd * wv4.y + bv4.y;
  o.z = (v.z - mu) * rstd * wv4.z + bv4.z;
  o.w = (v.w - mu) * rstd * wv4.w + bv4.w;
  ((float4*)(out + row * CC))[tid] = o;
}

__global__ __launch_bounds__(256) void ln_bf16_kernel(
    const float* __restrict__ x, const float* __restrict__ w,
    const float* __restrict__ b, unsigned short* __restrict__ out)
{
  size_t row = blockIdx.x;
  const float4* xr = (const float4*)(x + row * CC);
  int tid = threadIdx.x;
  float4 v = xr[tid];
  float s = v.x + v.y + v.z + v.w;
  float sq = v.x*v.x + v.y*v.y + v.z*v.z + v.w*v.w;
  for (int o = 32; o; o >>= 1) { s += __shfl_xor(s, o); sq += __shfl_xor(sq, o); }
  __shared__ float ss[4], ssq[4];
  int wv = tid >> 6, lane = tid & 63;
  if (lane == 0) { ss[wv] = s; ssq[wv] = sq; }
  __syncthreads();
  s = ss[0] + ss[1] + ss[2] + ss[3];
  sq = ssq[0] + ssq[1] + ssq[2] + ssq[3];
  float mu = s * (1.f / CC);
  float var = sq * (1.f / CC) - mu * mu;
  float rstd = rsqrtf(var + 1e-5f);
  float4 wv4 = ((const float4*)w)[tid];
  float4 bv4 = ((const float4*)b)[tid];
  ushort4 o;
  o.x = f2bf((v.x - mu) * rstd * wv4.x + bv4.x);
  o.y = f2bf((v.y - mu) * rstd * wv4.y + bv4.y);
  o.z = f2bf((v.z - mu) * rstd * wv4.z + bv4.z);
  o.w = f2bf((v.w - mu) * rstd * wv4.w + bv4.w);
  ((ushort4*)(out + row * CC))[tid] = o;
}

// ---------------- transpose h(B,T,C) -> hT(B,C,T) ----------------
__global__ __launch_bounds__(256) void transpose_kernel(
    const float* __restrict__ in, float* __restrict__ out)
{
  __shared__ float tile[64][65];
  size_t boff = (size_t)blockIdx.z * TT * CC;
  int r0 = blockIdx.y * 64;   // t dim
  int c0 = blockIdx.x * 64;   // c dim
  int tid = threadIdx.x;
#pragma unroll
  for (int i = 0; i < 16; ++i) {
    int idx = tid + i * 256;
    int r = idx >> 6, cx = idx & 63;
    tile[r][cx] = in[boff + (size_t)(r0 + r) * CC + c0 + cx];
  }
  __syncthreads();
#pragma unroll
  for (int i = 0; i < 16; ++i) {
    int idx = tid + i * 256;
    int r = idx >> 6, cx = idx & 63;
    out[boff + (size_t)(c0 + r) * TT + r0 + cx] = tile[cx][r];
  }
}

// ---------------- x2[b,t,c] = x[b,t,c] + y[b,c,t] ----------------
__global__ __launch_bounds__(256) void transadd_kernel(
    const float* __restrict__ y, const float* __restrict__ x,
    float* __restrict__ x2)
{
  __shared__ float tile[64][65];
  size_t boff = (size_t)blockIdx.z * TT * CC;
  int t0 = blockIdx.x * 64;
  int c0 = blockIdx.y * 64;
  int tid = threadIdx.x;
#pragma unroll
  for (int i = 0; i < 16; ++i) {
    int idx = tid + i * 256;
    int r = idx >> 6, cx = idx & 63;   // r: c-local, cx: t-local
    tile[r][cx] = y[boff + (size_t)(c0 + r) * TT + t0 + cx];
  }
  __syncthreads();
#pragma unroll
  for (int i = 0; i < 16; ++i) {
    int idx = tid + i * 256;
    int r = idx >> 6, cx = idx & 63;   // r: t-local, cx: c-local
    size_t off = boff + (size_t)(t0 + r) * CC + c0 + cx;
    x2[off] = x[off] + tile[cx][r];
  }
}

// ---------------- S4D: exact chunked scan, one block per (b,c) ----------------
__global__ __launch_bounds__(256) void s4d_kernel(
    const float* __restrict__ hT,      // (B, C, T)
    const float* __restrict__ log_tau, // (64)
    const float* __restrict__ log_dt,  // (1)
    const float* __restrict__ mix,     // (C, 64)
    const float* __restrict__ Dv,      // (C)
    float* __restrict__ y)             // (B, C, T)
{
  int bc = blockIdx.x;          // b*C + c
  int c = bc & (CC - 1);
  int tid = threadIdx.x;
  int lane = tid & 63, wv = tid >> 6;

  __shared__ float s_u[TT];        // 16 KB
  __shared__ float s_P[64][64];    // 16 KB: local states, then carry states
  __shared__ float s_A[64][64];    // 16 KB: A[j][t] = r_j^{t+1}
  __shared__ float s_K[64], s_mix[64], s_r[64], s_rL[64], s_a[64];

  // stage u row (coalesced float4)
  const float4* urow = (const float4*)(hT + (size_t)bc * TT);
#pragma unroll
  for (int i = 0; i < 4; ++i)
    ((float4*)s_u)[tid + i * 256] = urow[tid + i * 256];

  if (tid < 64) {
    float lt = log_tau[tid];
    float tau = (lt > 20.f) ? lt : log1pf(expf(lt));
    float ld = log_dt[0];
    float dt = (ld > 20.f) ? ld : log1pf(expf(ld));
    float a = tau * dt;
    s_a[tid] = a;
    s_r[tid] = expf(-a);
    s_rL[tid] = expf(-a * 64.f);
    s_mix[tid] = mix[c * 64 + tid];
  }
  __syncthreads();

  // fill A[j][t] = exp(-a_j*(t+1))
#pragma unroll
  for (int i = 0; i < 16; ++i) {
    int idx = tid + i * 256;
    int j = idx >> 6, tl = idx & 63;
    s_A[j][tl] = expf(-s_a[j] * (float)(tl + 1));
  }
  // phase A: per-chunk local end-states. wave wv handles chunks wv, wv+4, ...
  {
    float r = s_r[lane];
    for (int k = wv; k < 64; k += 4) {
      const float* uc = s_u + k * 64;
      float P = 0.f;
#pragma unroll 8
      for (int s = 0; s < 64; ++s) P = fmaf(r, P, uc[s]);
      s_P[k][lane] = P;
    }
  }
  __syncthreads();

  // wave 1: K[d] = sum_j mix_j * r_j^d  (uses A)
  if (wv == 1) {
    int d = lane;
    float acc = 0.f;
    if (d == 0) {
#pragma unroll 8
      for (int j = 0; j < 64; ++j) acc += s_mix[j];
    } else {
#pragma unroll 8
      for (int j = 0; j < 64; ++j) acc = fmaf(s_mix[j], s_A[j][d - 1], acc);
    }
    s_K[d] = acc;
  }
  // wave 0: chunk scan; replace s_P[k][j] with carry-state-before-chunk-k
  if (wv == 0) {
    float S = 0.f;
    float rL = s_rL[lane];
    for (int k = 0; k < 64; ++k) {
      float Pk = s_P[k][lane];
      s_P[k][lane] = S;           // carry before chunk k
      S = fmaf(rL, S, Pk);
    }
  }
  __syncthreads();

  // phase C: outputs. lane = t within chunk
  float Dc = Dv[c];
  float* yrow = y + (size_t)bc * TT;
  for (int k = wv; k < 64; k += 4) {
    int tg = k * 64 + lane;
    float acc = Dc * s_u[tg];
    // carry: sum_j (mix_j * C_j[k]) * r_j^{lane+1}
#pragma unroll 8
    for (int j = 0; j < 64; ++j) {
      float wj = s_mix[j] * s_P[k][j];
      acc = fmaf(wj, s_A[j][lane], acc);
    }
    // within-chunk FIR (exact, d <= lane)
    for (int d = 0; d <= lane; ++d)
      acc = fmaf(s_K[d], s_u[tg - d], acc);
    yrow[tg] = acc;
  }
}

// ---------------- f32 -> bf16 convert ----------------
__global__ __launch_bounds__(256) void cvt_bf16_kernel(
    const float* __restrict__ in, unsigned short* __restrict__ out)
{
  int i = blockIdx.x * 256 + threadIdx.x;
  float4 v = ((const float4*)in)[i];
  ushort4 o;
  o.x = f2bf(v.x); o.y = f2bf(v.y); o.z = f2bf(v.z); o.w = f2bf(v.w);
  ((ushort4*)out)[i] = o;
}

// ---------------- GEMM1 (half-H): act = gelu(A @ Bw^T + bias), bf16 out ----------------
// A (M, lda) bf16 row-major; Bw rows are output cols, row-stride ldb; Out width ldo.
__global__ __launch_bounds__(256) void gemm_gelu_kernel(
    const unsigned short* __restrict__ A, int lda,
    const unsigned short* __restrict__ Bw, int ldb,
    const float* __restrict__ bias, unsigned short* __restrict__ Out, int ldo,
    int K)
{
  __shared__ unsigned short sA[128 * 32];
  __shared__ unsigned short sB[128 * 32];
  int m0 = blockIdx.y * 128, n0 = blockIdx.x * 128;
  int tid = threadIdx.x, lane = tid & 63, wv = tid >> 6;
  int wm = wv >> 1, wn = wv & 1;

  f32x4 acc[4][4] = {};

  int idx0 = tid, idx1 = tid + 256;
  int r0 = idx0 >> 2, cg0 = (idx0 & 3) * 8;
  int r1 = idx1 >> 2, cg1 = (idx1 & 3) * 8;
  const unsigned short* Ab = A + (size_t)m0 * lda;
  const unsigned short* Bb = Bw + (size_t)n0 * ldb;

  int arow = wm * 64 + (lane & 15);
  int brow = wn * 64 + (lane & 15);
  int kk = (lane >> 4) * 8;

  for (int k0 = 0; k0 < K; k0 += 32) {
    gll16(Ab + (size_t)r0 * lda + k0 + cg0, sA + idx0 * 8);
    gll16(Ab + (size_t)r1 * lda + k0 + cg1, sA + idx1 * 8);
    gll16(Bb + (size_t)r0 * ldb + k0 + cg0, sB + idx0 * 8);
    gll16(Bb + (size_t)r1 * ldb + k0 + cg1, sB + idx1 * 8);
    __syncthreads();
    bf16x8 af[4], bfr[4];
#pragma unroll
    for (int mi = 0; mi < 4; ++mi)
      af[mi] = *(const bf16x8*)(sA + (arow + mi * 16) * 32 + kk);
#pragma unroll
    for (int ni = 0; ni < 4; ++ni)
      bfr[ni] = *(const bf16x8*)(sB + (brow + ni * 16) * 32 + kk);
#pragma unroll
    for (int mi = 0; mi < 4; ++mi)
#pragma unroll
      for (int ni = 0; ni < 4; ++ni)
        acc[mi][ni] = __builtin_amdgcn_mfma_f32_16x16x32_bf16(af[mi], bfr[ni], acc[mi][ni], 0, 0, 0);
    __syncthreads();
  }

#pragma unroll
  for (int mi = 0; mi < 4; ++mi) {
    int rbase = m0 + wm * 64 + mi * 16 + (lane >> 4) * 4;
#pragma unroll
    for (int ni = 0; ni < 4; ++ni) {
      int col = n0 + wn * 64 + ni * 16 + (lane & 15);
      float bcol = bias[col];
#pragma unroll
      for (int r = 0; r < 4; ++r) {
        float v = acc[mi][ni][r] + bcol;
        v = 0.5f * v * (1.f + erff(v * 0.70710678118f));
        Out[(size_t)(rbase + r) * ldo + col] = f2bf(v);
      }
    }
  }
}

// ---------------- GEMM2 (half-K pass): Out = acc (+bias) + add ----------------
// add may alias Out (pass 1); no __restrict__ on those.
__global__ __launch_bounds__(256) void gemm_acc_kernel(
    const unsigned short* __restrict__ A, int lda,
    const unsigned short* __restrict__ Bw, int ldb,
    const float* __restrict__ bias,       // may be null
    const float* add, float* Out, int K)
{
  __shared__ unsigned short sA[128 * 32];
  __shared__ unsigned short sB[128 * 32];
  int m0 = blockIdx.y * 128, n0 = blockIdx.x * 128;
  int tid = threadIdx.x, lane = tid & 63, wv = tid >> 6;
  int wm = wv >> 1, wn = wv & 1;

  f32x4 acc[4][4] = {};

  int idx0 = tid, idx1 = tid + 256;
  int r0 = idx0 >> 2, cg0 = (idx0 & 3) * 8;
  int r1 = idx1 >> 2, cg1 = (idx1 & 3) * 8;
  const unsigned short* Ab = A + (size_t)m0 * lda;
  const unsigned short* Bb = Bw + (size_t)n0 * ldb;

  int arow = wm * 64 + (lane & 15);
  int brow = wn * 64 + (lane & 15);
  int kk = (lane >> 4) * 8;

  for (int k0 = 0; k0 < K; k0 += 32) {
    gll16(Ab + (size_t)r0 * lda + k0 + cg0, sA + idx0 * 8);
    gll16(Ab + (size_t)r1 * lda + k0 + cg1, sA + idx1 * 8);
    gll16(Bb + (size_t)r0 * ldb + k0 + cg0, sB + idx0 * 8);
    gll16(Bb + (size_t)r1 * ldb + k0 + cg1, sB + idx1 * 8);
    __syncthreads();
    bf16x8 af[4], bfr[4];
#pragma unroll
    for (int mi = 0; mi < 4; ++mi)
      af[mi] = *(const bf16x8*)(sA + (arow + mi * 16) * 32 + kk);
#pragma unroll
    for (int ni = 0; ni < 4; ++ni)
      bfr[ni] = *(const bf16x8*)(sB + (brow + ni * 16) * 32 + kk);
#pragma unroll
    for (int mi = 0; mi < 4; ++mi)
#pragma unroll
      for (int ni = 0; ni < 4; ++ni)
        acc[mi][ni] = __builtin_amdgcn_mfma_f32_16x16x32_bf16(af[mi], bfr[ni], acc[mi][ni], 0, 0, 0);
    __syncthreads();
  }

#pragma unroll
  for (int mi = 0; mi < 4; ++mi) {
    int rbase = m0 + wm * 64 + mi * 16 + (lane >> 4) * 4;
#pragma unroll
    for (int ni = 0; ni < 4; ++ni) {
      int col = n0 + wn * 64 + ni * 16 + (lane & 15);
      float bcol = bias ? bias[col] : 0.f;
#pragma unroll
      for (int r = 0; r < 4; ++r) {
        size_t off = (size_t)(rbase + r) * CC + col;
        Out[off] = acc[mi][ni][r] + bcol + add[off];
      }
    }
  }
}

// ---------------- launch ----------------
extern "C" void kernel_launch(void* const* d_in, const int* in_sizes, int n_in,
                              void* d_out, int out_size, void* d_ws, size_t ws_size,
                              hipStream_t stream)
{
  const float* x       = (const float*)d_in[0];
  const float* log_tau = (const float*)d_in[1];
  const float* log_dt  = (const float*)d_in[2];
  const float* mix     = (const float*)d_in[3];
  const float* Dv      = (const float*)d_in[4];
  const float* n1w     = (const float*)d_in[5];
  const float* n1b     = (const float*)d_in[6];
  const float* n2w     = (const float*)d_in[7];
  const float* n2b     = (const float*)d_in[8];
  const float* w1      = (const float*)d_in[9];
  const float* b1      = (const float*)d_in[10];
  const float* w2      = (const float*)d_in[11];
  const float* b2      = (const float*)d_in[12];

  // workspace layout (176 MB total):
  //   buf0: 64 MB  (h -> y -> act bf16 half, aliased)
  //   buf1: 64 MB  (hT -> x2)
  //   a2:   32 MB  (LN2 output bf16)
  //   w1b:   8 MB, w2b: 8 MB
  char* ws = (char*)d_ws;
  float* buf0 = (float*)ws;
  float* buf1 = (float*)(ws + (64ull << 20));
  unsigned short* a2  = (unsigned short*)(ws + (128ull << 20));
  unsigned short* w1b = (unsigned short*)(ws + (160ull << 20));
  unsigned short* w2b = (unsigned short*)(ws + (168ull << 20));
  unsigned short* act = (unsigned short*)buf0;   // alias: M x 2048 bf16 = 64 MB
  float* out = (float*)d_out;

  // 1. h = LN1(x)
  ln_f32_kernel<<<MM, 256, 0, stream>>>(x, n1w, n1b, buf0);
  // 2. hT = transpose(h)
  transpose_kernel<<<dim3(CC / 64, TT / 64, BB), 256, 0, stream>>>(buf0, buf1);
  // 3. y = s4d(hT)   (y -> buf0)
  s4d_kernel<<<BB * CC, 256, 0, stream>>>(buf1, log_tau, log_dt, mix, Dv, buf0);
  // 4. x2 = x + y^T  (x2 -> buf1)
  transadd_kernel<<<dim3(TT / 64, CC / 64, BB), 256, 0, stream>>>(buf0, x, buf1);
  // 5. a2 = bf16(LN2(x2))   (buf0/y now dead -> act aliases it)
  ln_bf16_kernel<<<MM, 256, 0, stream>>>(buf1, n2w, n2b, a2);
  // 6. weight casts
  cvt_bf16_kernel<<<(HH * CC / 4) / 256, 256, 0, stream>>>(w1, w1b);
  cvt_bf16_kernel<<<(HH * CC / 4) / 256, 256, 0, stream>>>(w2, w2b);

  // 7/8. MLP split along H into two halves of 2048 (act buffer = 64 MB)
  // half 0
  gemm_gelu_kernel<<<dim3(2048 / 128, MM / 128), 256, 0, stream>>>(
      a2, CC, w1b, CC, b1, act, 2048, CC);
  gemm_acc_kernel<<<dim3(CC / 128, MM / 128), 256, 0, stream>>>(
      act, 2048, w2b, HH, b2, buf1, out, 2048);
  // half 1
  gemm_gelu_kernel<<<dim3(2048 / 128, MM / 128), 256, 0, stream>>>(
      a2, CC, w1b + (size_t)2048 * CC, CC, b1 + 2048, act, 2048, CC);
  gemm_acc_kernel<<<dim3(CC / 128, MM / 128), 256, 0, stream>>>(
      act, 2048, w2b + 2048, HH, (const float*)nullptr, out, out, 2048);
}

// Round 3
// 856.553 us; speedup vs baseline: 1.2315x; 1.2315x over previous
//
#include <hip/hip_runtime.h>
#include <math.h>

// ---------------- common ----------------
typedef __attribute__((ext_vector_type(8))) short bf16x8;
typedef __attribute__((ext_vector_type(4))) float f32x4;

__device__ __forceinline__ unsigned short f2bf(float f) {
  union { float f; unsigned u; } v; v.f = f;
  unsigned r = v.u + 0x7fff + ((v.u >> 16) & 1);
  return (unsigned short)(r >> 16);
}

__device__ __forceinline__ float bf2f(unsigned short h) {
  union { unsigned u; float f; } v; v.u = ((unsigned)h) << 16;
  return v.f;
}

__device__ __forceinline__ void gll16(const void* g, void* l) {
  __builtin_amdgcn_global_load_lds(
      (const __attribute__((address_space(1))) void*)g,
      (__attribute__((address_space(3))) void*)l, 16, 0, 0);
}

#define BB 4
#define TT 4096
#define CC 1024
#define HH 4096
#define MM 16384   // B*T

// ---------------- LayerNorm (one block per row, C=1024) ----------------
__global__ __launch_bounds__(256) void ln_f32_kernel(
    const float* __restrict__ x, const float* __restrict__ w,
    const float* __restrict__ b, float* __restrict__ out)
{
  size_t row = blockIdx.x;
  const float4* xr = (const float4*)(x + row * CC);
  int tid = threadIdx.x;
  float4 v = xr[tid];
  float s = v.x + v.y + v.z + v.w;
  float sq = v.x*v.x + v.y*v.y + v.z*v.z + v.w*v.w;
  for (int o = 32; o; o >>= 1) { s += __shfl_xor(s, o); sq += __shfl_xor(sq, o); }
  __shared__ float ss[4], ssq[4];
  int wv = tid >> 6, lane = tid & 63;
  if (lane == 0) { ss[wv] = s; ssq[wv] = sq; }
  __syncthreads();
  s = ss[0] + ss[1] + ss[2] + ss[3];
  sq = ssq[0] + ssq[1] + ssq[2] + ssq[3];
  float mu = s * (1.f / CC);
  float var = sq * (1.f / CC) - mu * mu;
  float rstd = rsqrtf(var + 1e-5f);
  float4 wv4 = ((const float4*)w)[tid];
  float4 bv4 = ((const float4*)b)[tid];
  float4 o;
  o.x = (v.x - mu) * rstd * wv4.x + bv4.x;
  o.y = (v.y - mu) * rstd * wv4.y + bv4.y;
  o.z = (v.z - mu) * rstd * wv4.z + bv4.z;
  o.w = (v.w - mu) * rstd * wv4.w + bv4.w;
  ((float4*)(out + row * CC))[tid] = o;
}

__global__ __launch_bounds__(256) void ln_bf16_kernel(
    const float* __restrict__ x, const float* __restrict__ w,
    const float* __restrict__ b, unsigned short* __restrict__ out)
{
  size_t row = blockIdx.x;
  const float4* xr = (const float4*)(x + row * CC);
  int tid = threadIdx.x;
  float4 v = xr[tid];
  float s = v.x + v.y + v.z + v.w;
  float sq = v.x*v.x + v.y*v.y + v.z*v.z + v.w*v.w;
  for (int o = 32; o; o >>= 1) { s += __shfl_xor(s, o); sq += __shfl_xor(sq, o); }
  __shared__ float ss[4], ssq[4];
  int wv = tid >> 6, lane = tid & 63;
  if (lane == 0) { ss[wv] = s; ssq[wv] = sq; }
  __syncthreads();
  s = ss[0] + ss[1] + ss[2] + ss[3];
  sq = ssq[0] + ssq[1] + ssq[2] + ssq[3];
  float mu = s * (1.f / CC);
  float var = sq * (1.f / CC) - mu * mu;
  float rstd = rsqrtf(var + 1e-5f);
  float4 wv4 = ((const float4*)w)[tid];
  float4 bv4 = ((const float4*)b)[tid];
  ushort4 o;
  o.x = f2bf((v.x - mu) * rstd * wv4.x + bv4.x);
  o.y = f2bf((v.y - mu) * rstd * wv4.y + bv4.y);
  o.z = f2bf((v.z - mu) * rstd * wv4.z + bv4.z);
  o.w = f2bf((v.w - mu) * rstd * wv4.w + bv4.w);
  ((ushort4*)(out + row * CC))[tid] = o;
}

// ---------------- transpose h(B,T,C) -> hT(B,C,T) ----------------
__global__ __launch_bounds__(256) void transpose_kernel(
    const float* __restrict__ in, float* __restrict__ out)
{
  __shared__ float tile[64][65];
  size_t boff = (size_t)blockIdx.z * TT * CC;
  int r0 = blockIdx.y * 64;   // t dim
  int c0 = blockIdx.x * 64;   // c dim
  int tid = threadIdx.x;
#pragma unroll
  for (int i = 0; i < 16; ++i) {
    int idx = tid + i * 256;
    int r = idx >> 6, cx = idx & 63;
    tile[r][cx] = in[boff + (size_t)(r0 + r) * CC + c0 + cx];
  }
  __syncthreads();
#pragma unroll
  for (int i = 0; i < 16; ++i) {
    int idx = tid + i * 256;
    int r = idx >> 6, cx = idx & 63;
    out[boff + (size_t)(c0 + r) * TT + r0 + cx] = tile[cx][r];
  }
}

// ---------------- x2[b,t,c] = x[b,t,c] + y[b,c,t] ----------------
__global__ __launch_bounds__(256) void transadd_kernel(
    const float* __restrict__ y, const float* __restrict__ x,
    float* __restrict__ x2)
{
  __shared__ float tile[64][65];
  size_t boff = (size_t)blockIdx.z * TT * CC;
  int t0 = blockIdx.x * 64;
  int c0 = blockIdx.y * 64;
  int tid = threadIdx.x;
#pragma unroll
  for (int i = 0; i < 16; ++i) {
    int idx = tid + i * 256;
    int r = idx >> 6, cx = idx & 63;   // r: c-local, cx: t-local
    tile[r][cx] = y[boff + (size_t)(c0 + r) * TT + t0 + cx];
  }
  __syncthreads();
#pragma unroll
  for (int i = 0; i < 16; ++i) {
    int idx = tid + i * 256;
    int r = idx >> 6, cx = idx & 63;   // r: t-local, cx: c-local
    size_t off = boff + (size_t)(t0 + r) * CC + c0 + cx;
    x2[off] = x[off] + tile[cx][r];
  }
}

// ---------------- S4D via MFMA: one block per (b,c) row ----------------
// Per row (T=4096, L=64 chunks of 64):
//   U[s][k] = u[k*64+s]  (B-operand, stored [k-row][s-col] bf16 hi/lo)
//   P  = A2 @ U,  A2[j][s] = r_j^(63-s)          (local chunk-end states)
//   scan: S[k+1] = r_j^64 * S[k] + P[j][k]; W[j][k] = mix_j * S[k]
//   Y  = Ac @ W + T @ U,  Ac[t][j] = r_j^(t+1), T[t][s] = K[t-s] (s<=t)
//   y[k*64+t] = Y[t][k] + D_c * u[k*64+t]
// All 64x64 bf16 LDS tiles XOR-swizzled (G4): byte ^= (row&7)<<4.
#define SWZ(row, byteoff) (((row) << 7) + ((byteoff) ^ (((row) & 7) << 4)))

__global__ __launch_bounds__(256) void s4d_kernel(
    const float* __restrict__ hT,      // (B, C, T)
    const float* __restrict__ log_tau, // (64)
    const float* __restrict__ log_dt,  // (1)
    const float* __restrict__ mix,     // (C, 64)
    const float* __restrict__ Dv,      // (C)
    float* __restrict__ y)             // (B, C, T)
{
  int bc = blockIdx.x;
  int c = bc & (CC - 1);
  int tid = threadIdx.x;
  int lane = tid & 63, w = tid >> 6;
  int m = lane & 15, g = lane >> 4;

  __shared__ unsigned short s_uh[64 * 64], s_ul[64 * 64];
  __shared__ unsigned short s_A2[64 * 64], s_Ac[64 * 64];
  __shared__ unsigned short s_T[64 * 64], s_Wt[64 * 64];
  __shared__ float s_P[64 * 64];
  __shared__ float s_a[64], s_rL[64], s_mix[64], s_K[64], s_Kp[4 * 64];

  // ---- stage u -> bf16 hi/lo (swizzled) ----
  const float4* urow = (const float4*)(hT + (size_t)bc * TT);
#pragma unroll
  for (int q = 0; q < 4; ++q) {
    int i = tid + q * 256;           // float4 index in row
    float4 v = urow[i];
    int row = i >> 4;                // chunk index k
    int colb = (i & 15) * 8;         // byte offset of s within row
    float f[4] = {v.x, v.y, v.z, v.w};
    ushort4 hh, ll;
    unsigned short* hp = (unsigned short*)&hh;
    unsigned short* lp = (unsigned short*)&ll;
#pragma unroll
    for (int r = 0; r < 4; ++r) {
      unsigned short hb = f2bf(f[r]);
      hp[r] = hb;
      lp[r] = f2bf(f[r] - bf2f(hb));
    }
    *(ushort4*)((char*)s_uh + SWZ(row, colb)) = hh;
    *(ushort4*)((char*)s_ul + SWZ(row, colb)) = ll;
  }
  if (tid < 64) {
    float lt = log_tau[tid];
    float tau = (lt > 20.f) ? lt : log1pf(expf(lt));
    float ld = log_dt[0];
    float dt = (ld > 20.f) ? ld : log1pf(expf(ld));
    float a = tau * dt;
    s_a[tid] = a;
    s_rL[tid] = expf(-64.f * a);
    s_mix[tid] = mix[c * 64 + tid];
  }
  __syncthreads();   // (1) u, params ready

  // ---- build A2, Ac ----
#pragma unroll
  for (int e = 0; e < 16; ++e) {
    int idx = tid + e * 256;
    int rA = idx >> 6, cA = idx & 63;
    s_A2[SWZ(rA, cA * 2) >> 1] = f2bf(expf(-s_a[rA] * (float)(63 - cA)));
    s_Ac[SWZ(rA, cA * 2) >> 1] = f2bf(expf(-s_a[cA] * (float)(rA + 1)));
  }
  __syncthreads();   // (2) A2/Ac ready

  // ---- K partials: K[d] = sum_j mix_j r_j^d ; Ac[d-1][j] = r_j^d ----
  {
    int d = tid & 63, q = tid >> 6;
    float p = 0.f;
    if (d == 0) {
#pragma unroll
      for (int j = 16 * q; j < 16 * q + 16; ++j) p += s_mix[j];
    } else {
#pragma unroll
      for (int j = 16 * q; j < 16 * q + 16; ++j)
        p = fmaf(s_mix[j], bf2f(s_Ac[SWZ(d - 1, j * 2) >> 1]), p);
    }
    s_Kp[q * 64 + d] = p;
  }

  // ---- phase 1: P = A2 @ (Uh + Ul) ----
  {
    f32x4 accP[4] = {};
    bf16x8 a2f[2];
#pragma unroll
    for (int ks = 0; ks < 2; ++ks)
      a2f[ks] = *(const bf16x8*)((const char*)s_A2 + SWZ(16 * w + m, ks * 64 + g * 16));
#pragma unroll
    for (int ct = 0; ct < 4; ++ct) {
#pragma unroll
      for (int ks = 0; ks < 2; ++ks) {
        bf16x8 bh = *(const bf16x8*)((const char*)s_uh + SWZ(ct * 16 + m, ks * 64 + g * 16));
        bf16x8 bl = *(const bf16x8*)((const char*)s_ul + SWZ(ct * 16 + m, ks * 64 + g * 16));
        accP[ct] = __builtin_amdgcn_mfma_f32_16x16x32_bf16(a2f[ks], bh, accP[ct], 0, 0, 0);
        accP[ct] = __builtin_amdgcn_mfma_f32_16x16x32_bf16(a2f[ks], bl, accP[ct], 0, 0, 0);
      }
    }
    // write P[k][j] (f32, unswizzled; acc: col k = lane&15(+16ct), rows j = 16w+g*4+r)
#pragma unroll
    for (int ct = 0; ct < 4; ++ct)
      *(f32x4*)&s_P[(ct * 16 + m) * 64 + 16 * w + g * 4] = accP[ct];
  }
  __syncthreads();   // (3) Kp + P ready

  if (tid < 64)
    s_K[tid] = s_Kp[tid] + s_Kp[64 + tid] + s_Kp[128 + tid] + s_Kp[192 + tid];
  __syncthreads();   // (4) K ready

  // ---- build T[t][s] = K[t-s] for s<=t ----
#pragma unroll
  for (int e = 0; e < 16; ++e) {
    int idx = tid + e * 256;
    int t = idx >> 6, s = idx & 63;
    float val = (s <= t) ? s_K[t - s] : 0.f;
    s_T[SWZ(t, s * 2) >> 1] = f2bf(val);
  }
  // ---- scan (lane j): W[j][k] = mix_j * S_before[k], stored Wt[k][j] ----
  if (tid < 64) {
    int j = tid;
    float S = 0.f, rL = s_rL[j], mj = s_mix[j];
    for (int k = 0; k < 64; ++k) {
      s_Wt[SWZ(k, j * 2) >> 1] = f2bf(mj * S);
      S = fmaf(rL, S, s_P[k * 64 + j]);
    }
  }
  __syncthreads();   // (5) T + Wt ready

  // ---- phase 2: Y = Ac @ W + T @ (Uh + Ul) ----
  f32x4 accY[4] = {};
  {
    bf16x8 acf[2], tf[2];
#pragma unroll
    for (int ks = 0; ks < 2; ++ks) {
      acf[ks] = *(const bf16x8*)((const char*)s_Ac + SWZ(16 * w + m, ks * 64 + g * 16));
      tf[ks]  = *(const bf16x8*)((const char*)s_T  + SWZ(16 * w + m, ks * 64 + g * 16));
    }
#pragma unroll
    for (int ct = 0; ct < 4; ++ct) {
#pragma unroll
      for (int ks = 0; ks < 2; ++ks) {
        bf16x8 bw  = *(const bf16x8*)((const char*)s_Wt + SWZ(ct * 16 + m, ks * 64 + g * 16));
        bf16x8 uhf = *(const bf16x8*)((const char*)s_uh + SWZ(ct * 16 + m, ks * 64 + g * 16));
        bf16x8 ulf = *(const bf16x8*)((const char*)s_ul + SWZ(ct * 16 + m, ks * 64 + g * 16));
        accY[ct] = __builtin_amdgcn_mfma_f32_16x16x32_bf16(acf[ks], bw,  accY[ct], 0, 0, 0);
        accY[ct] = __builtin_amdgcn_mfma_f32_16x16x32_bf16(tf[ks],  uhf, accY[ct], 0, 0, 0);
        accY[ct] = __builtin_amdgcn_mfma_f32_16x16x32_bf16(tf[ks],  ulf, accY[ct], 0, 0, 0);
      }
    }
  }

  // ---- epilogue: y[k*64+t] = Y[t][k] + D_c * u ----
  float Dc = Dv[c];
  float* yrow = y + (size_t)bc * TT;
#pragma unroll
  for (int ct = 0; ct < 4; ++ct) {
    int k = ct * 16 + m;
    int t0 = 16 * w + g * 4;
    float4 o;
    float* op = (float*)&o;
#pragma unroll
    for (int r = 0; r < 4; ++r) {
      int t = t0 + r;
      float uf = bf2f(s_uh[SWZ(k, t * 2) >> 1]) + bf2f(s_ul[SWZ(k, t * 2) >> 1]);
      op[r] = accY[ct][r] + Dc * uf;
    }
    *(float4*)(yrow + k * 64 + t0) = o;
  }
}

// ---------------- f32 -> bf16 convert ----------------
__global__ __launch_bounds__(256) void cvt_bf16_kernel(
    const float* __restrict__ in, unsigned short* __restrict__ out)
{
  int i = blockIdx.x * 256 + threadIdx.x;
  float4 v = ((const float4*)in)[i];
  ushort4 o;
  o.x = f2bf(v.x); o.y = f2bf(v.y); o.z = f2bf(v.z); o.w = f2bf(v.w);
  ((ushort4*)out)[i] = o;
}

// ---------------- GEMM1 (half-H): act = gelu(A @ Bw^T + bias), bf16 out ----------------
__global__ __launch_bounds__(256) void gemm_gelu_kernel(
    const unsigned short* __restrict__ A, int lda,
    const unsigned short* __restrict__ Bw, int ldb,
    const float* __restrict__ bias, unsigned short* __restrict__ Out, int ldo,
    int K)
{
  __shared__ unsigned short sA[128 * 32];
  __shared__ unsigned short sB[128 * 32];
  int m0 = blockIdx.y * 128, n0 = blockIdx.x * 128;
  int tid = threadIdx.x, lane = tid & 63, wv = tid >> 6;
  int wm = wv >> 1, wn = wv & 1;

  f32x4 acc[4][4] = {};

  int idx0 = tid, idx1 = tid + 256;
  int r0 = idx0 >> 2, cg0 = (idx0 & 3) * 8;
  int r1 = idx1 >> 2, cg1 = (idx1 & 3) * 8;
  const unsigned short* Ab = A + (size_t)m0 * lda;
  const unsigned short* Bb = Bw + (size_t)n0 * ldb;

  int arow = wm * 64 + (lane & 15);
  int brow = wn * 64 + (lane & 15);
  int kk = (lane >> 4) * 8;

  for (int k0 = 0; k0 < K; k0 += 32) {
    gll16(Ab + (size_t)r0 * lda + k0 + cg0, sA + idx0 * 8);
    gll16(Ab + (size_t)r1 * lda + k0 + cg1, sA + idx1 * 8);
    gll16(Bb + (size_t)r0 * ldb + k0 + cg0, sB + idx0 * 8);
    gll16(Bb + (size_t)r1 * ldb + k0 + cg1, sB + idx1 * 8);
    __syncthreads();
    bf16x8 af[4], bfr[4];
#pragma unroll
    for (int mi = 0; mi < 4; ++mi)
      af[mi] = *(const bf16x8*)(sA + (arow + mi * 16) * 32 + kk);
#pragma unroll
    for (int ni = 0; ni < 4; ++ni)
      bfr[ni] = *(const bf16x8*)(sB + (brow + ni * 16) * 32 + kk);
#pragma unroll
    for (int mi = 0; mi < 4; ++mi)
#pragma unroll
      for (int ni = 0; ni < 4; ++ni)
        acc[mi][ni] = __builtin_amdgcn_mfma_f32_16x16x32_bf16(af[mi], bfr[ni], acc[mi][ni], 0, 0, 0);
    __syncthreads();
  }

#pragma unroll
  for (int mi = 0; mi < 4; ++mi) {
    int rbase = m0 + wm * 64 + mi * 16 + (lane >> 4) * 4;
#pragma unroll
    for (int ni = 0; ni < 4; ++ni) {
      int col = n0 + wn * 64 + ni * 16 + (lane & 15);
      float bcol = bias[col];
#pragma unroll
      for (int r = 0; r < 4; ++r) {
        float v = acc[mi][ni][r] + bcol;
        v = 0.5f * v * (1.f + erff(v * 0.70710678118f));
        Out[(size_t)(rbase + r) * ldo + col] = f2bf(v);
      }
    }
  }
}

// ---------------- GEMM2 (half-K pass): Out = acc (+bias) + add ----------------
__global__ __launch_bounds__(256) void gemm_acc_kernel(
    const unsigned short* __restrict__ A, int lda,
    const unsigned short* __restrict__ Bw, int ldb,
    const float* __restrict__ bias,       // may be null
    const float* add, float* Out, int K)
{
  __shared__ unsigned short sA[128 * 32];
  __shared__ unsigned short sB[128 * 32];
  int m0 = blockIdx.y * 128, n0 = blockIdx.x * 128;
  int tid = threadIdx.x, lane = tid & 63, wv = tid >> 6;
  int wm = wv >> 1, wn = wv & 1;

  f32x4 acc[4][4] = {};

  int idx0 = tid, idx1 = tid + 256;
  int r0 = idx0 >> 2, cg0 = (idx0 & 3) * 8;
  int r1 = idx1 >> 2, cg1 = (idx1 & 3) * 8;
  const unsigned short* Ab = A + (size_t)m0 * lda;
  const unsigned short* Bb = Bw + (size_t)n0 * ldb;

  int arow = wm * 64 + (lane & 15);
  int brow = wn * 64 + (lane & 15);
  int kk = (lane >> 4) * 8;

  for (int k0 = 0; k0 < K; k0 += 32) {
    gll16(Ab + (size_t)r0 * lda + k0 + cg0, sA + idx0 * 8);
    gll16(Ab + (size_t)r1 * lda + k0 + cg1, sA + idx1 * 8);
    gll16(Bb + (size_t)r0 * ldb + k0 + cg0, sB + idx0 * 8);
    gll16(Bb + (size_t)r1 * ldb + k0 + cg1, sB + idx1 * 8);
    __syncthreads();
    bf16x8 af[4], bfr[4];
#pragma unroll
    for (int mi = 0; mi < 4; ++mi)
      af[mi] = *(const bf16x8*)(sA + (arow + mi * 16) * 32 + kk);
#pragma unroll
    for (int ni = 0; ni < 4; ++ni)
      bfr[ni] = *(const bf16x8*)(sB + (brow + ni * 16) * 32 + kk);
#pragma unroll
    for (int mi = 0; mi < 4; ++mi)
#pragma unroll
      for (int ni = 0; ni < 4; ++ni)
        acc[mi][ni] = __builtin_amdgcn_mfma_f32_16x16x32_bf16(af[mi], bfr[ni], acc[mi][ni], 0, 0, 0);
    __syncthreads();
  }

#pragma unroll
  for (int mi = 0; mi < 4; ++mi) {
    int rbase = m0 + wm * 64 + mi * 16 + (lane >> 4) * 4;
#pragma unroll
    for (int ni = 0; ni < 4; ++ni) {
      int col = n0 + wn * 64 + ni * 16 + (lane & 15);
      float bcol = bias ? bias[col] : 0.f;
#pragma unroll
      for (int r = 0; r < 4; ++r) {
        size_t off = (size_t)(rbase + r) * CC + col;
        Out[off] = acc[mi][ni][r] + bcol + add[off];
      }
    }
  }
}

// ---------------- launch ----------------
extern "C" void kernel_launch(void* const* d_in, const int* in_sizes, int n_in,
                              void* d_out, int out_size, void* d_ws, size_t ws_size,
                              hipStream_t stream)
{
  const float* x       = (const float*)d_in[0];
  const float* log_tau = (const float*)d_in[1];
  const float* log_dt  = (const float*)d_in[2];
  const float* mix     = (const float*)d_in[3];
  const float* Dv      = (const float*)d_in[4];
  const float* n1w     = (const float*)d_in[5];
  const float* n1b     = (const float*)d_in[6];
  const float* n2w     = (const float*)d_in[7];
  const float* n2b     = (const float*)d_in[8];
  const float* w1      = (const float*)d_in[9];
  const float* b1      = (const float*)d_in[10];
  const float* w2      = (const float*)d_in[11];
  const float* b2      = (const float*)d_in[12];

  // workspace layout (176 MB total):
  //   buf0: 64 MB  (h -> y -> act bf16 half, aliased)
  //   buf1: 64 MB  (hT -> x2)
  //   a2:   32 MB  (LN2 output bf16)
  //   w1b:   8 MB, w2b: 8 MB
  char* ws = (char*)d_ws;
  float* buf0 = (float*)ws;
  float* buf1 = (float*)(ws + (64ull << 20));
  unsigned short* a2  = (unsigned short*)(ws + (128ull << 20));
  unsigned short* w1b = (unsigned short*)(ws + (160ull << 20));
  unsigned short* w2b = (unsigned short*)(ws + (168ull << 20));
  unsigned short* act = (unsigned short*)buf0;   // alias: M x 2048 bf16 = 64 MB
  float* out = (float*)d_out;

  // 1. h = LN1(x)
  ln_f32_kernel<<<MM, 256, 0, stream>>>(x, n1w, n1b, buf0);
  // 2. hT = transpose(h)
  transpose_kernel<<<dim3(CC / 64, TT / 64, BB), 256, 0, stream>>>(buf0, buf1);
  // 3. y = s4d(hT)   (y -> buf0)
  s4d_kernel<<<BB * CC, 256, 0, stream>>>(buf1, log_tau, log_dt, mix, Dv, buf0);
  // 4. x2 = x + y^T  (x2 -> buf1)
  transadd_kernel<<<dim3(TT / 64, CC / 64, BB), 256, 0, stream>>>(buf0, x, buf1);
  // 5. a2 = bf16(LN2(x2))   (buf0/y now dead -> act aliases it)
  ln_bf16_kernel<<<MM, 256, 0, stream>>>(buf1, n2w, n2b, a2);
  // 6. weight casts
  cvt_bf16_kernel<<<(HH * CC / 4) / 256, 256, 0, stream>>>(w1, w1b);
  cvt_bf16_kernel<<<(HH * CC / 4) / 256, 256, 0, stream>>>(w2, w2b);

  // 7/8. MLP split along H into two halves of 2048 (act buffer = 64 MB)
  // half 0
  gemm_gelu_kernel<<<dim3(2048 / 128, MM / 128), 256, 0, stream>>>(
      a2, CC, w1b, CC, b1, act, 2048, CC);
  gemm_acc_kernel<<<dim3(CC / 128, MM / 128), 256, 0, stream>>>(
      act, 2048, w2b, HH, b2, buf1, out, 2048);
  // half 1
  gemm_gelu_kernel<<<dim3(2048 / 128, MM / 128), 256, 0, stream>>>(
      a2, CC, w1b + (size_t)2048 * CC, CC, b1 + 2048, act, 2048, CC);
  gemm_acc_kernel<<<dim3(CC / 128, MM / 128), 256, 0, stream>>>(
      act, 2048, w2b + 2048, HH, (const float*)nullptr, out, out, 2048);
}

// Round 5
// 830.905 us; speedup vs baseline: 1.2695x; 1.0309x over previous
//
#include <hip/hip_runtime.h>
#include <math.h>

// ---------------- common ----------------
typedef __attribute__((ext_vector_type(8))) short bf16x8;
typedef __attribute__((ext_vector_type(4))) float f32x4;

__device__ __forceinline__ unsigned short f2bf(float f) {
  union { float f; unsigned u; } v; v.f = f;
  unsigned r = v.u + 0x7fff + ((v.u >> 16) & 1);
  return (unsigned short)(r >> 16);
}

__device__ __forceinline__ float bf2f(unsigned short h) {
  union { unsigned u; float f; } v; v.u = ((unsigned)h) << 16;
  return v.f;
}

__device__ __forceinline__ void gll16(const void* g, void* l) {
  __builtin_amdgcn_global_load_lds(
      (const __attribute__((address_space(1))) void*)g,
      (__attribute__((address_space(3))) void*)l, 16, 0, 0);
}

#define BB 4
#define TT 4096
#define CC 1024
#define HH 4096
#define MM 16384   // B*T

// ---------------- LayerNorm (one block per row, C=1024) ----------------
__global__ __launch_bounds__(256) void ln_f32_kernel(
    const float* __restrict__ x, const float* __restrict__ w,
    const float* __restrict__ b, float* __restrict__ out)
{
  size_t row = blockIdx.x;
  const float4* xr = (const float4*)(x + row * CC);
  int tid = threadIdx.x;
  float4 v = xr[tid];
  float s = v.x + v.y + v.z + v.w;
  float sq = v.x*v.x + v.y*v.y + v.z*v.z + v.w*v.w;
  for (int o = 32; o; o >>= 1) { s += __shfl_xor(s, o); sq += __shfl_xor(sq, o); }
  __shared__ float ss[4], ssq[4];
  int wv = tid >> 6, lane = tid & 63;
  if (lane == 0) { ss[wv] = s; ssq[wv] = sq; }
  __syncthreads();
  s = ss[0] + ss[1] + ss[2] + ss[3];
  sq = ssq[0] + ssq[1] + ssq[2] + ssq[3];
  float mu = s * (1.f / CC);
  float var = sq * (1.f / CC) - mu * mu;
  float rstd = rsqrtf(var + 1e-5f);
  float4 wv4 = ((const float4*)w)[tid];
  float4 bv4 = ((const float4*)b)[tid];
  float4 o;
  o.x = (v.x - mu) * rstd * wv4.x + bv4.x;
  o.y = (v.y - mu) * rstd * wv4.y + bv4.y;
  o.z = (v.z - mu) * rstd * wv4.z + bv4.z;
  o.w = (v.w - mu) * rstd * wv4.w + bv4.w;
  ((float4*)(out + row * CC))[tid] = o;
}

__global__ __launch_bounds__(256) void ln_bf16_kernel(
    const float* __restrict__ x, const float* __restrict__ w,
    const float* __restrict__ b, unsigned short* __restrict__ out)
{
  size_t row = blockIdx.x;
  const float4* xr = (const float4*)(x + row * CC);
  int tid = threadIdx.x;
  float4 v = xr[tid];
  float s = v.x + v.y + v.z + v.w;
  float sq = v.x*v.x + v.y*v.y + v.z*v.z + v.w*v.w;
  for (int o = 32; o; o >>= 1) { s += __shfl_xor(s, o); sq += __shfl_xor(sq, o); }
  __shared__ float ss[4], ssq[4];
  int wv = tid >> 6, lane = tid & 63;
  if (lane == 0) { ss[wv] = s; ssq[wv] = sq; }
  __syncthreads();
  s = ss[0] + ss[1] + ss[2] + ss[3];
  sq = ssq[0] + ssq[1] + ssq[2] + ssq[3];
  float mu = s * (1.f / CC);
  float var = sq * (1.f / CC) - mu * mu;
  float rstd = rsqrtf(var + 1e-5f);
  float4 wv4 = ((const float4*)w)[tid];
  float4 bv4 = ((const float4*)b)[tid];
  ushort4 o;
  o.x = f2bf((v.x - mu) * rstd * wv4.x + bv4.x);
  o.y = f2bf((v.y - mu) * rstd * wv4.y + bv4.y);
  o.z = f2bf((v.z - mu) * rstd * wv4.z + bv4.z);
  o.w = f2bf((v.w - mu) * rstd * wv4.w + bv4.w);
  ((ushort4*)(out + row * CC))[tid] = o;
}

// ---------------- transpose h(B,T,C) -> hT(B,C,T) ----------------
__global__ __launch_bounds__(256) void transpose_kernel(
    const float* __restrict__ in, float* __restrict__ out)
{
  __shared__ float tile[64][65];
  size_t boff = (size_t)blockIdx.z * TT * CC;
  int r0 = blockIdx.y * 64;   // t dim
  int c0 = blockIdx.x * 64;   // c dim
  int tid = threadIdx.x;
#pragma unroll
  for (int i = 0; i < 16; ++i) {
    int idx = tid + i * 256;
    int r = idx >> 6, cx = idx & 63;
    tile[r][cx] = in[boff + (size_t)(r0 + r) * CC + c0 + cx];
  }
  __syncthreads();
#pragma unroll
  for (int i = 0; i < 16; ++i) {
    int idx = tid + i * 256;
    int r = idx >> 6, cx = idx & 63;
    out[boff + (size_t)(c0 + r) * TT + r0 + cx] = tile[cx][r];
  }
}

// ---------------- x2[b,t,c] = x[b,t,c] + y[b,c,t] ----------------
__global__ __launch_bounds__(256) void transadd_kernel(
    const float* __restrict__ y, const float* __restrict__ x,
    float* __restrict__ x2)
{
  __shared__ float tile[64][65];
  size_t boff = (size_t)blockIdx.z * TT * CC;
  int t0 = blockIdx.x * 64;
  int c0 = blockIdx.y * 64;
  int tid = threadIdx.x;
#pragma unroll
  for (int i = 0; i < 16; ++i) {
    int idx = tid + i * 256;
    int r = idx >> 6, cx = idx & 63;   // r: c-local, cx: t-local
    tile[r][cx] = y[boff + (size_t)(c0 + r) * TT + t0 + cx];
  }
  __syncthreads();
#pragma unroll
  for (int i = 0; i < 16; ++i) {
    int idx = tid + i * 256;
    int r = idx >> 6, cx = idx & 63;   // r: t-local, cx: c-local
    size_t off = boff + (size_t)(t0 + r) * CC + c0 + cx;
    x2[off] = x[off] + tile[cx][r];
  }
}

// ---------------- S4D via MFMA: one block per (b,c) row ----------------
#define SWZ(row, byteoff) (((row) << 7) + ((byteoff) ^ (((row) & 7) << 4)))

__global__ __launch_bounds__(256) void s4d_kernel(
    const float* __restrict__ hT,      // (B, C, T)
    const float* __restrict__ log_tau, // (64)
    const float* __restrict__ log_dt,  // (1)
    const float* __restrict__ mix,     // (C, 64)
    const float* __restrict__ Dv,      // (C)
    float* __restrict__ y)             // (B, C, T)
{
  int bc = blockIdx.x;
  int c = bc & (CC - 1);
  int tid = threadIdx.x;
  int lane = tid & 63, w = tid >> 6;
  int m = lane & 15, g = lane >> 4;

  __shared__ unsigned short s_uh[64 * 64], s_ul[64 * 64];
  __shared__ unsigned short s_A2[64 * 64], s_Ac[64 * 64];
  __shared__ unsigned short s_T[64 * 64], s_Wt[64 * 64];
  __shared__ float s_P[64 * 64];
  __shared__ float s_a[64], s_rL[64], s_mix[64], s_K[64], s_Kp[4 * 64];

  // ---- stage u -> bf16 hi/lo (swizzled) ----
  const float4* urow = (const float4*)(hT + (size_t)bc * TT);
#pragma unroll
  for (int q = 0; q < 4; ++q) {
    int i = tid + q * 256;           // float4 index in row
    float4 v = urow[i];
    int row = i >> 4;                // chunk index k
    int colb = (i & 15) * 8;         // byte offset of s within row
    float f[4] = {v.x, v.y, v.z, v.w};
    ushort4 hh, ll;
    unsigned short* hp = (unsigned short*)&hh;
    unsigned short* lp = (unsigned short*)&ll;
#pragma unroll
    for (int r = 0; r < 4; ++r) {
      unsigned short hb = f2bf(f[r]);
      hp[r] = hb;
      lp[r] = f2bf(f[r] - bf2f(hb));
    }
    *(ushort4*)((char*)s_uh + SWZ(row, colb)) = hh;
    *(ushort4*)((char*)s_ul + SWZ(row, colb)) = ll;
  }
  if (tid < 64) {
    float lt = log_tau[tid];
    float tau = (lt > 20.f) ? lt : log1pf(expf(lt));
    float ld = log_dt[0];
    float dt = (ld > 20.f) ? ld : log1pf(expf(ld));
    float a = tau * dt;
    s_a[tid] = a;
    s_rL[tid] = expf(-64.f * a);
    s_mix[tid] = mix[c * 64 + tid];
  }
  __syncthreads();   // (1) u, params ready

  // ---- build A2, Ac ----
#pragma unroll
  for (int e = 0; e < 16; ++e) {
    int idx = tid + e * 256;
    int rA = idx >> 6, cA = idx & 63;
    s_A2[SWZ(rA, cA * 2) >> 1] = f2bf(expf(-s_a[rA] * (float)(63 - cA)));
    s_Ac[SWZ(rA, cA * 2) >> 1] = f2bf(expf(-s_a[cA] * (float)(rA + 1)));
  }
  __syncthreads();   // (2) A2/Ac ready

  // ---- K partials ----
  {
    int d = tid & 63, q = tid >> 6;
    float p = 0.f;
    if (d == 0) {
#pragma unroll
      for (int j = 16 * q; j < 16 * q + 16; ++j) p += s_mix[j];
    } else {
#pragma unroll
      for (int j = 16 * q; j < 16 * q + 16; ++j)
        p = fmaf(s_mix[j], bf2f(s_Ac[SWZ(d - 1, j * 2) >> 1]), p);
    }
    s_Kp[q * 64 + d] = p;
  }

  // ---- phase 1: P = A2 @ (Uh + Ul) ----
  {
    f32x4 accP[4] = {};
    bf16x8 a2f[2];
#pragma unroll
    for (int ks = 0; ks < 2; ++ks)
      a2f[ks] = *(const bf16x8*)((const char*)s_A2 + SWZ(16 * w + m, ks * 64 + g * 16));
#pragma unroll
    for (int ct = 0; ct < 4; ++ct) {
#pragma unroll
      for (int ks = 0; ks < 2; ++ks) {
        bf16x8 bh = *(const bf16x8*)((const char*)s_uh + SWZ(ct * 16 + m, ks * 64 + g * 16));
        bf16x8 bl = *(const bf16x8*)((const char*)s_ul + SWZ(ct * 16 + m, ks * 64 + g * 16));
        accP[ct] = __builtin_amdgcn_mfma_f32_16x16x32_bf16(a2f[ks], bh, accP[ct], 0, 0, 0);
        accP[ct] = __builtin_amdgcn_mfma_f32_16x16x32_bf16(a2f[ks], bl, accP[ct], 0, 0, 0);
      }
    }
#pragma unroll
    for (int ct = 0; ct < 4; ++ct)
      *(f32x4*)&s_P[(ct * 16 + m) * 64 + 16 * w + g * 4] = accP[ct];
  }
  __syncthreads();   // (3) Kp + P ready

  if (tid < 64)
    s_K[tid] = s_Kp[tid] + s_Kp[64 + tid] + s_Kp[128 + tid] + s_Kp[192 + tid];
  __syncthreads();   // (4) K ready

  // ---- build T[t][s] = K[t-s] for s<=t ----
#pragma unroll
  for (int e = 0; e < 16; ++e) {
    int idx = tid + e * 256;
    int t = idx >> 6, s = idx & 63;
    float val = (s <= t) ? s_K[t - s] : 0.f;
    s_T[SWZ(t, s * 2) >> 1] = f2bf(val);
  }
  // ---- scan (lane j): W[j][k] = mix_j * S_before[k], stored Wt[k][j] ----
  if (tid < 64) {
    int j = tid;
    float S = 0.f, rL = s_rL[j], mj = s_mix[j];
    for (int k = 0; k < 64; ++k) {
      s_Wt[SWZ(k, j * 2) >> 1] = f2bf(mj * S);
      S = fmaf(rL, S, s_P[k * 64 + j]);
    }
  }
  __syncthreads();   // (5) T + Wt ready

  // ---- phase 2: Y = Ac @ W + T @ (Uh + Ul) ----
  f32x4 accY[4] = {};
  {
    bf16x8 acf[2], tf[2];
#pragma unroll
    for (int ks = 0; ks < 2; ++ks) {
      acf[ks] = *(const bf16x8*)((const char*)s_Ac + SWZ(16 * w + m, ks * 64 + g * 16));
      tf[ks]  = *(const bf16x8*)((const char*)s_T  + SWZ(16 * w + m, ks * 64 + g * 16));
    }
#pragma unroll
    for (int ct = 0; ct < 4; ++ct) {
#pragma unroll
      for (int ks = 0; ks < 2; ++ks) {
        bf16x8 bw  = *(const bf16x8*)((const char*)s_Wt + SWZ(ct * 16 + m, ks * 64 + g * 16));
        bf16x8 uhf = *(const bf16x8*)((const char*)s_uh + SWZ(ct * 16 + m, ks * 64 + g * 16));
        bf16x8 ulf = *(const bf16x8*)((const char*)s_ul + SWZ(ct * 16 + m, ks * 64 + g * 16));
        accY[ct] = __builtin_amdgcn_mfma_f32_16x16x32_bf16(acf[ks], bw,  accY[ct], 0, 0, 0);
        accY[ct] = __builtin_amdgcn_mfma_f32_16x16x32_bf16(tf[ks],  uhf, accY[ct], 0, 0, 0);
        accY[ct] = __builtin_amdgcn_mfma_f32_16x16x32_bf16(tf[ks],  ulf, accY[ct], 0, 0, 0);
      }
    }
  }

  // ---- epilogue: y[k*64+t] = Y[t][k] + D_c * u ----
  float Dc = Dv[c];
  float* yrow = y + (size_t)bc * TT;
#pragma unroll
  for (int ct = 0; ct < 4; ++ct) {
    int k = ct * 16 + m;
    int t0 = 16 * w + g * 4;
    float4 o;
    float* op = (float*)&o;
#pragma unroll
    for (int r = 0; r < 4; ++r) {
      int t = t0 + r;
      float uf = bf2f(s_uh[SWZ(k, t * 2) >> 1]) + bf2f(s_ul[SWZ(k, t * 2) >> 1]);
      op[r] = accY[ct][r] + Dc * uf;
    }
    *(float4*)(yrow + k * 64 + t0) = o;
  }
}

// ---------------- f32 -> bf16 convert ----------------
__global__ __launch_bounds__(256) void cvt_bf16_kernel(
    const float* __restrict__ in, unsigned short* __restrict__ out)
{
  int i = blockIdx.x * 256 + threadIdx.x;
  float4 v = ((const float4*)in)[i];
  ushort4 o;
  o.x = f2bf(v.x); o.y = f2bf(v.y); o.z = f2bf(v.z); o.w = f2bf(v.w);
  ((ushort4*)out)[i] = o;
}

// ---------------- GEMM1 (half-H): act = gelu(A @ Bw^T + bias), bf16 out ----------------
// 1D grid, XCD-aware chunk swizzle (T1): each XCD owns contiguous m-panels.
// NB = N/128 blocks per row-panel; nwg = NB * (M/128), nwg % 8 == 0.
__global__ __launch_bounds__(256) void gemm_gelu_kernel(
    const unsigned short* __restrict__ A, int lda,
    const unsigned short* __restrict__ Bw, int ldb,
    const float* __restrict__ bias, unsigned short* __restrict__ Out, int ldo,
    int K, int NB, int cpx)
{
  __shared__ unsigned short sA[128 * 32];
  __shared__ unsigned short sB[128 * 32];
  int id = blockIdx.x;
  int swz = (id & 7) * cpx + (id >> 3);
  int m0 = (swz / NB) * 128, n0 = (swz % NB) * 128;
  int tid = threadIdx.x, lane = tid & 63, wv = tid >> 6;
  int wm = wv >> 1, wn = wv & 1;

  f32x4 acc[4][4] = {};

  int idx0 = tid, idx1 = tid + 256;
  int r0 = idx0 >> 2, cg0 = (idx0 & 3) * 8;
  int r1 = idx1 >> 2, cg1 = (idx1 & 3) * 8;
  const unsigned short* Ab = A + (size_t)m0 * lda;
  const unsigned short* Bb = Bw + (size_t)n0 * ldb;

  int arow = wm * 64 + (lane & 15);
  int brow = wn * 64 + (lane & 15);
  int kk = (lane >> 4) * 8;

  for (int k0 = 0; k0 < K; k0 += 32) {
    gll16(Ab + (size_t)r0 * lda + k0 + cg0, sA + idx0 * 8);
    gll16(Ab + (size_t)r1 * lda + k0 + cg1, sA + idx1 * 8);
    gll16(Bb + (size_t)r0 * ldb + k0 + cg0, sB + idx0 * 8);
    gll16(Bb + (size_t)r1 * ldb + k0 + cg1, sB + idx1 * 8);
    __syncthreads();
    bf16x8 af[4], bfr[4];
#pragma unroll
    for (int mi = 0; mi < 4; ++mi)
      af[mi] = *(const bf16x8*)(sA + (arow + mi * 16) * 32 + kk);
#pragma unroll
    for (int ni = 0; ni < 4; ++ni)
      bfr[ni] = *(const bf16x8*)(sB + (brow + ni * 16) * 32 + kk);
#pragma unroll
    for (int mi = 0; mi < 4; ++mi)
#pragma unroll
      for (int ni = 0; ni < 4; ++ni)
        acc[mi][ni] = __builtin_amdgcn_mfma_f32_16x16x32_bf16(af[mi], bfr[ni], acc[mi][ni], 0, 0, 0);
    __syncthreads();
  }

#pragma unroll
  for (int mi = 0; mi < 4; ++mi) {
    int rbase = m0 + wm * 64 + mi * 16 + (lane >> 4) * 4;
#pragma unroll
    for (int ni = 0; ni < 4; ++ni) {
      int col = n0 + wn * 64 + ni * 16 + (lane & 15);
      float bcol = bias[col];
#pragma unroll
      for (int r = 0; r < 4; ++r) {
        float v = acc[mi][ni][r] + bcol;
        v = 0.5f * v * (1.f + erff(v * 0.70710678118f));
        Out[(size_t)(rbase + r) * ldo + col] = f2bf(v);
      }
    }
  }
}

// ---------------- GEMM2 (half-K pass): Out = acc (+bias) + add ----------------
__global__ __launch_bounds__(256) void gemm_acc_kernel(
    const unsigned short* __restrict__ A, int lda,
    const unsigned short* __restrict__ Bw, int ldb,
    const float* __restrict__ bias,       // may be null
    const float* add, float* Out, int K, int NB, int cpx)
{
  __shared__ unsigned short sA[128 * 32];
  __shared__ unsigned short sB[128 * 32];
  int id = blockIdx.x;
  int swz = (id & 7) * cpx + (id >> 3);
  int m0 = (swz / NB) * 128, n0 = (swz % NB) * 128;
  int tid = threadIdx.x, lane = tid & 63, wv = tid >> 6;
  int wm = wv >> 1, wn = wv & 1;

  f32x4 acc[4][4] = {};

  int idx0 = tid, idx1 = tid + 256;
  int r0 = idx0 >> 2, cg0 = (idx0 & 3) * 8;
  int r1 = idx1 >> 2, cg1 = (idx1 & 3) * 8;
  const unsigned short* Ab = A + (size_t)m0 * lda;
  const unsigned short* Bb = Bw + (size_t)n0 * ldb;

  int arow = wm * 64 + (lane & 15);
  int brow = wn * 64 + (lane & 15);
  int kk = (lane >> 4) * 8;

  for (int k0 = 0; k0 < K; k0 += 32) {
    gll16(Ab + (size_t)r0 * lda + k0 + cg0, sA + idx0 * 8);
    gll16(Ab + (size_t)r1 * lda + k0 + cg1, sA + idx1 * 8);
    gll16(Bb + (size_t)r0 * ldb + k0 + cg0, sB + idx0 * 8);
    gll16(Bb + (size_t)r1 * ldb + k0 + cg1, sB + idx1 * 8);
    __syncthreads();
    bf16x8 af[4], bfr[4];
#pragma unroll
    for (int mi = 0; mi < 4; ++mi)
      af[mi] = *(const bf16x8*)(sA + (arow + mi * 16) * 32 + kk);
#pragma unroll
    for (int ni = 0; ni < 4; ++ni)
      bfr[ni] = *(const bf16x8*)(sB + (brow + ni * 16) * 32 + kk);
#pragma unroll
    for (int mi = 0; mi < 4; ++mi)
#pragma unroll
      for (int ni = 0; ni < 4; ++ni)
        acc[mi][ni] = __builtin_amdgcn_mfma_f32_16x16x32_bf16(af[mi], bfr[ni], acc[mi][ni], 0, 0, 0);
    __syncthreads();
  }

#pragma unroll
  for (int mi = 0; mi < 4; ++mi) {
    int rbase = m0 + wm * 64 + mi * 16 + (lane >> 4) * 4;
#pragma unroll
    for (int ni = 0; ni < 4; ++ni) {
      int col = n0 + wn * 64 + ni * 16 + (lane & 15);
      float bcol = bias ? bias[col] : 0.f;
#pragma unroll
      for (int r = 0; r < 4; ++r) {
        size_t off = (size_t)(rbase + r) * CC + col;
        Out[off] = acc[mi][ni][r] + bcol + add[off];
      }
    }
  }
}

// ---------------- launch ----------------
extern "C" void kernel_launch(void* const* d_in, const int* in_sizes, int n_in,
                              void* d_out, int out_size, void* d_ws, size_t ws_size,
                              hipStream_t stream)
{
  const float* x       = (const float*)d_in[0];
  const float* log_tau = (const float*)d_in[1];
  const float* log_dt  = (const float*)d_in[2];
  const float* mix     = (const float*)d_in[3];
  const float* Dv      = (const float*)d_in[4];
  const float* n1w     = (const float*)d_in[5];
  const float* n1b     = (const float*)d_in[6];
  const float* n2w     = (const float*)d_in[7];
  const float* n2b     = (const float*)d_in[8];
  const float* w1      = (const float*)d_in[9];
  const float* b1      = (const float*)d_in[10];
  const float* w2      = (const float*)d_in[11];
  const float* b2      = (const float*)d_in[12];

  // workspace layout (176 MB total)
  char* ws = (char*)d_ws;
  float* buf0 = (float*)ws;
  float* buf1 = (float*)(ws + (64ull << 20));
  unsigned short* a2  = (unsigned short*)(ws + (128ull << 20));
  unsigned short* w1b = (unsigned short*)(ws + (160ull << 20));
  unsigned short* w2b = (unsigned short*)(ws + (168ull << 20));
  unsigned short* act = (unsigned short*)buf0;   // alias: M x 2048 bf16 = 64 MB
  float* out = (float*)d_out;

  // 1. h = LN1(x)
  ln_f32_kernel<<<MM, 256, 0, stream>>>(x, n1w, n1b, buf0);
  // 2. hT = transpose(h)
  transpose_kernel<<<dim3(CC / 64, TT / 64, BB), 256, 0, stream>>>(buf0, buf1);
  // 3. y = s4d(hT)   (y -> buf0)
  s4d_kernel<<<BB * CC, 256, 0, stream>>>(buf1, log_tau, log_dt, mix, Dv, buf0);
  // 4. x2 = x + y^T  (x2 -> buf1)
  transadd_kernel<<<dim3(TT / 64, CC / 64, BB), 256, 0, stream>>>(buf0, x, buf1);
  // 5. a2 = bf16(LN2(x2))   (buf0/y now dead -> act aliases it)
  ln_bf16_kernel<<<MM, 256, 0, stream>>>(buf1, n2w, n2b, a2);
  // 6. weight casts
  cvt_bf16_kernel<<<(HH * CC / 4) / 256, 256, 0, stream>>>(w1, w1b);
  cvt_bf16_kernel<<<(HH * CC / 4) / 256, 256, 0, stream>>>(w2, w2b);

  // 7/8. MLP split along H into two halves of 2048 (act buffer = 64 MB)
  // gemm_gelu: NB=16 (2048/128), nwg=2048, cpx=256
  // gemm_acc:  NB=8  (1024/128), nwg=1024, cpx=128
  // half 0
  gemm_gelu_kernel<<<2048, 256, 0, stream>>>(
      a2, CC, w1b, CC, b1, act, 2048, CC, 16, 256);
  gemm_acc_kernel<<<1024, 256, 0, stream>>>(
      act, 2048, w2b, HH, b2, buf1, out, 2048, 8, 128);
  // half 1
  gemm_gelu_kernel<<<2048, 256, 0, stream>>>(
      a2, CC, w1b + (size_t)2048 * CC, CC, b1 + 2048, act, 2048, CC, 16, 256);
  gemm_acc_kernel<<<1024, 256, 0, stream>>>(
      act, 2048, w2b + 2048, HH, (const float*)nullptr, out, out, 2048, 8, 128);
}

// Round 6
// 813.516 us; speedup vs baseline: 1.2966x; 1.0214x over previous
//
#include <hip/hip_runtime.h>
#include <math.h>

// ---------------- common ----------------
typedef __attribute__((ext_vector_type(8))) short bf16x8;
typedef __attribute__((ext_vector_type(4))) float f32x4;

__device__ __forceinline__ unsigned short f2bf(float f) {
  union { float f; unsigned u; } v; v.f = f;
  unsigned r = v.u + 0x7fff + ((v.u >> 16) & 1);
  return (unsigned short)(r >> 16);
}

__device__ __forceinline__ float bf2f(unsigned short h) {
  union { unsigned u; float f; } v; v.u = ((unsigned)h) << 16;
  return v.f;
}

__device__ __forceinline__ void gll16(const void* g, void* l) {
  __builtin_amdgcn_global_load_lds(
      (const __attribute__((address_space(1))) void*)g,
      (__attribute__((address_space(3))) void*)l, 16, 0, 0);
}

#define BB 4
#define TT 4096
#define CC 1024
#define HH 4096
#define MM 16384   // B*T

// ---------------- LayerNorm (one block per row, C=1024) ----------------
__global__ __launch_bounds__(256) void ln_f32_kernel(
    const float* __restrict__ x, const float* __restrict__ w,
    const float* __restrict__ b, float* __restrict__ out)
{
  size_t row = blockIdx.x;
  const float4* xr = (const float4*)(x + row * CC);
  int tid = threadIdx.x;
  float4 v = xr[tid];
  float s = v.x + v.y + v.z + v.w;
  float sq = v.x*v.x + v.y*v.y + v.z*v.z + v.w*v.w;
  for (int o = 32; o; o >>= 1) { s += __shfl_xor(s, o); sq += __shfl_xor(sq, o); }
  __shared__ float ss[4], ssq[4];
  int wv = tid >> 6, lane = tid & 63;
  if (lane == 0) { ss[wv] = s; ssq[wv] = sq; }
  __syncthreads();
  s = ss[0] + ss[1] + ss[2] + ss[3];
  sq = ssq[0] + ssq[1] + ssq[2] + ssq[3];
  float mu = s * (1.f / CC);
  float var = sq * (1.f / CC) - mu * mu;
  float rstd = rsqrtf(var + 1e-5f);
  float4 wv4 = ((const float4*)w)[tid];
  float4 bv4 = ((const float4*)b)[tid];
  float4 o;
  o.x = (v.x - mu) * rstd * wv4.x + bv4.x;
  o.y = (v.y - mu) * rstd * wv4.y + bv4.y;
  o.z = (v.z - mu) * rstd * wv4.z + bv4.z;
  o.w = (v.w - mu) * rstd * wv4.w + bv4.w;
  ((float4*)(out + row * CC))[tid] = o;
}

__global__ __launch_bounds__(256) void ln_bf16_kernel(
    const float* __restrict__ x, const float* __restrict__ w,
    const float* __restrict__ b, unsigned short* __restrict__ out)
{
  size_t row = blockIdx.x;
  const float4* xr = (const float4*)(x + row * CC);
  int tid = threadIdx.x;
  float4 v = xr[tid];
  float s = v.x + v.y + v.z + v.w;
  float sq = v.x*v.x + v.y*v.y + v.z*v.z + v.w*v.w;
  for (int o = 32; o; o >>= 1) { s += __shfl_xor(s, o); sq += __shfl_xor(sq, o); }
  __shared__ float ss[4], ssq[4];
  int wv = tid >> 6, lane = tid & 63;
  if (lane == 0) { ss[wv] = s; ssq[wv] = sq; }
  __syncthreads();
  s = ss[0] + ss[1] + ss[2] + ss[3];
  sq = ssq[0] + ssq[1] + ssq[2] + ssq[3];
  float mu = s * (1.f / CC);
  float var = sq * (1.f / CC) - mu * mu;
  float rstd = rsqrtf(var + 1e-5f);
  float4 wv4 = ((const float4*)w)[tid];
  float4 bv4 = ((const float4*)b)[tid];
  ushort4 o;
  o.x = f2bf((v.x - mu) * rstd * wv4.x + bv4.x);
  o.y = f2bf((v.y - mu) * rstd * wv4.y + bv4.y);
  o.z = f2bf((v.z - mu) * rstd * wv4.z + bv4.z);
  o.w = f2bf((v.w - mu) * rstd * wv4.w + bv4.w);
  ((ushort4*)(out + row * CC))[tid] = o;
}

// ---------------- transpose h(B,T,C) -> hT(B,C,T) ----------------
__global__ __launch_bounds__(256) void transpose_kernel(
    const float* __restrict__ in, float* __restrict__ out)
{
  __shared__ float tile[64][65];
  size_t boff = (size_t)blockIdx.z * TT * CC;
  int r0 = blockIdx.y * 64;   // t dim
  int c0 = blockIdx.x * 64;   // c dim
  int tid = threadIdx.x;
#pragma unroll
  for (int i = 0; i < 16; ++i) {
    int idx = tid + i * 256;
    int r = idx >> 6, cx = idx & 63;
    tile[r][cx] = in[boff + (size_t)(r0 + r) * CC + c0 + cx];
  }
  __syncthreads();
#pragma unroll
  for (int i = 0; i < 16; ++i) {
    int idx = tid + i * 256;
    int r = idx >> 6, cx = idx & 63;
    out[boff + (size_t)(c0 + r) * TT + r0 + cx] = tile[cx][r];
  }
}

// ---------------- x2[b,t,c] = x[b,t,c] + y[b,c,t] ----------------
__global__ __launch_bounds__(256) void transadd_kernel(
    const float* __restrict__ y, const float* __restrict__ x,
    float* __restrict__ x2)
{
  __shared__ float tile[64][65];
  size_t boff = (size_t)blockIdx.z * TT * CC;
  int t0 = blockIdx.x * 64;
  int c0 = blockIdx.y * 64;
  int tid = threadIdx.x;
#pragma unroll
  for (int i = 0; i < 16; ++i) {
    int idx = tid + i * 256;
    int r = idx >> 6, cx = idx & 63;   // r: c-local, cx: t-local
    tile[r][cx] = y[boff + (size_t)(c0 + r) * TT + t0 + cx];
  }
  __syncthreads();
#pragma unroll
  for (int i = 0; i < 16; ++i) {
    int idx = tid + i * 256;
    int r = idx >> 6, cx = idx & 63;   // r: t-local, cx: c-local
    size_t off = boff + (size_t)(t0 + r) * CC + c0 + cx;
    x2[off] = x[off] + tile[cx][r];
  }
}

// ---------------- S4D via MFMA: one block per (b,c) row ----------------
#define SWZ(row, byteoff) (((row) << 7) + ((byteoff) ^ (((row) & 7) << 4)))

__global__ __launch_bounds__(256) void s4d_kernel(
    const float* __restrict__ hT,      // (B, C, T)
    const float* __restrict__ log_tau, // (64)
    const float* __restrict__ log_dt,  // (1)
    const float* __restrict__ mix,     // (C, 64)
    const float* __restrict__ Dv,      // (C)
    float* __restrict__ y)             // (B, C, T)
{
  int bc = blockIdx.x;
  int c = bc & (CC - 1);
  int tid = threadIdx.x;
  int lane = tid & 63, w = tid >> 6;
  int m = lane & 15, g = lane >> 4;

  __shared__ unsigned short s_uh[64 * 64], s_ul[64 * 64];
  __shared__ unsigned short s_A2[64 * 64], s_Ac[64 * 64];
  __shared__ unsigned short s_T[64 * 64], s_Wt[64 * 64];
  __shared__ float s_P[64 * 64];
  __shared__ float s_a[64], s_rL[64], s_mix[64], s_K[64], s_Kp[4 * 64];

  // ---- stage u -> bf16 hi/lo (swizzled) ----
  const float4* urow = (const float4*)(hT + (size_t)bc * TT);
#pragma unroll
  for (int q = 0; q < 4; ++q) {
    int i = tid + q * 256;           // float4 index in row
    float4 v = urow[i];
    int row = i >> 4;                // chunk index k
    int colb = (i & 15) * 8;         // byte offset of s within row
    float f[4] = {v.x, v.y, v.z, v.w};
    ushort4 hh, ll;
    unsigned short* hp = (unsigned short*)&hh;
    unsigned short* lp = (unsigned short*)&ll;
#pragma unroll
    for (int r = 0; r < 4; ++r) {
      unsigned short hb = f2bf(f[r]);
      hp[r] = hb;
      lp[r] = f2bf(f[r] - bf2f(hb));
    }
    *(ushort4*)((char*)s_uh + SWZ(row, colb)) = hh;
    *(ushort4*)((char*)s_ul + SWZ(row, colb)) = ll;
  }
  if (tid < 64) {
    float lt = log_tau[tid];
    float tau = (lt > 20.f) ? lt : log1pf(expf(lt));
    float ld = log_dt[0];
    float dt = (ld > 20.f) ? ld : log1pf(expf(ld));
    float a = tau * dt;
    s_a[tid] = a;
    s_rL[tid] = expf(-64.f * a);
    s_mix[tid] = mix[c * 64 + tid];
  }
  __syncthreads();   // (1) u, params ready

  // ---- build A2, Ac ----
#pragma unroll
  for (int e = 0; e < 16; ++e) {
    int idx = tid + e * 256;
    int rA = idx >> 6, cA = idx & 63;
    s_A2[SWZ(rA, cA * 2) >> 1] = f2bf(expf(-s_a[rA] * (float)(63 - cA)));
    s_Ac[SWZ(rA, cA * 2) >> 1] = f2bf(expf(-s_a[cA] * (float)(rA + 1)));
  }
  __syncthreads();   // (2) A2/Ac ready

  // ---- K partials ----
  {
    int d = tid & 63, q = tid >> 6;
    float p = 0.f;
    if (d == 0) {
#pragma unroll
      for (int j = 16 * q; j < 16 * q + 16; ++j) p += s_mix[j];
    } else {
#pragma unroll
      for (int j = 16 * q; j < 16 * q + 16; ++j)
        p = fmaf(s_mix[j], bf2f(s_Ac[SWZ(d - 1, j * 2) >> 1]), p);
    }
    s_Kp[q * 64 + d] = p;
  }

  // ---- phase 1: P = A2 @ (Uh + Ul) ----
  {
    f32x4 accP[4] = {};
    bf16x8 a2f[2];
#pragma unroll
    for (int ks = 0; ks < 2; ++ks)
      a2f[ks] = *(const bf16x8*)((const char*)s_A2 + SWZ(16 * w + m, ks * 64 + g * 16));
#pragma unroll
    for (int ct = 0; ct < 4; ++ct) {
#pragma unroll
      for (int ks = 0; ks < 2; ++ks) {
        bf16x8 bh = *(const bf16x8*)((const char*)s_uh + SWZ(ct * 16 + m, ks * 64 + g * 16));
        bf16x8 bl = *(const bf16x8*)((const char*)s_ul + SWZ(ct * 16 + m, ks * 64 + g * 16));
        accP[ct] = __builtin_amdgcn_mfma_f32_16x16x32_bf16(a2f[ks], bh, accP[ct], 0, 0, 0);
        accP[ct] = __builtin_amdgcn_mfma_f32_16x16x32_bf16(a2f[ks], bl, accP[ct], 0, 0, 0);
      }
    }
#pragma unroll
    for (int ct = 0; ct < 4; ++ct)
      *(f32x4*)&s_P[(ct * 16 + m) * 64 + 16 * w + g * 4] = accP[ct];
  }
  __syncthreads();   // (3) Kp + P ready

  if (tid < 64)
    s_K[tid] = s_Kp[tid] + s_Kp[64 + tid] + s_Kp[128 + tid] + s_Kp[192 + tid];
  __syncthreads();   // (4) K ready

  // ---- build T[t][s] = K[t-s] for s<=t ----
#pragma unroll
  for (int e = 0; e < 16; ++e) {
    int idx = tid + e * 256;
    int t = idx >> 6, s = idx & 63;
    float val = (s <= t) ? s_K[t - s] : 0.f;
    s_T[SWZ(t, s * 2) >> 1] = f2bf(val);
  }
  // ---- scan (lane j): W[j][k] = mix_j * S_before[k], stored Wt[k][j] ----
  if (tid < 64) {
    int j = tid;
    float S = 0.f, rL = s_rL[j], mj = s_mix[j];
    for (int k = 0; k < 64; ++k) {
      s_Wt[SWZ(k, j * 2) >> 1] = f2bf(mj * S);
      S = fmaf(rL, S, s_P[k * 64 + j]);
    }
  }
  __syncthreads();   // (5) T + Wt ready

  // ---- phase 2: Y = Ac @ W + T @ (Uh + Ul) ----
  f32x4 accY[4] = {};
  {
    bf16x8 acf[2], tf[2];
#pragma unroll
    for (int ks = 0; ks < 2; ++ks) {
      acf[ks] = *(const bf16x8*)((const char*)s_Ac + SWZ(16 * w + m, ks * 64 + g * 16));
      tf[ks]  = *(const bf16x8*)((const char*)s_T  + SWZ(16 * w + m, ks * 64 + g * 16));
    }
#pragma unroll
    for (int ct = 0; ct < 4; ++ct) {
#pragma unroll
      for (int ks = 0; ks < 2; ++ks) {
        bf16x8 bw  = *(const bf16x8*)((const char*)s_Wt + SWZ(ct * 16 + m, ks * 64 + g * 16));
        bf16x8 uhf = *(const bf16x8*)((const char*)s_uh + SWZ(ct * 16 + m, ks * 64 + g * 16));
        bf16x8 ulf = *(const bf16x8*)((const char*)s_ul + SWZ(ct * 16 + m, ks * 64 + g * 16));
        accY[ct] = __builtin_amdgcn_mfma_f32_16x16x32_bf16(acf[ks], bw,  accY[ct], 0, 0, 0);
        accY[ct] = __builtin_amdgcn_mfma_f32_16x16x32_bf16(tf[ks],  uhf, accY[ct], 0, 0, 0);
        accY[ct] = __builtin_amdgcn_mfma_f32_16x16x32_bf16(tf[ks],  ulf, accY[ct], 0, 0, 0);
      }
    }
  }

  // ---- epilogue: y[k*64+t] = Y[t][k] + D_c * u ----
  float Dc = Dv[c];
  float* yrow = y + (size_t)bc * TT;
#pragma unroll
  for (int ct = 0; ct < 4; ++ct) {
    int k = ct * 16 + m;
    int t0 = 16 * w + g * 4;
    float4 o;
    float* op = (float*)&o;
#pragma unroll
    for (int r = 0; r < 4; ++r) {
      int t = t0 + r;
      float uf = bf2f(s_uh[SWZ(k, t * 2) >> 1]) + bf2f(s_ul[SWZ(k, t * 2) >> 1]);
      op[r] = accY[ct][r] + Dc * uf;
    }
    *(float4*)(yrow + k * 64 + t0) = o;
  }
}

// ---------------- f32 -> bf16 convert ----------------
__global__ __launch_bounds__(256) void cvt_bf16_kernel(
    const float* __restrict__ in, unsigned short* __restrict__ out)
{
  int i = blockIdx.x * 256 + threadIdx.x;
  float4 v = ((const float4*)in)[i];
  ushort4 o;
  o.x = f2bf(v.x); o.y = f2bf(v.y); o.z = f2bf(v.z); o.w = f2bf(v.w);
  ((ushort4*)out)[i] = o;
}

// ---------------- GEMM1 (half-H): act = gelu(A @ Bw^T + bias), bf16 out ----------------
// T1 XCD chunk swizzle + T3-lite 2-phase LDS double-buffer:
// stage tile t+1 BEFORE computing tile t; single __syncthreads per K-step
// (its vmcnt(0) drain lands after the MFMAs -> load latency overlaps compute).
__global__ __launch_bounds__(256) void gemm_gelu_kernel(
    const unsigned short* __restrict__ A, int lda,
    const unsigned short* __restrict__ Bw, int ldb,
    const float* __restrict__ bias, unsigned short* __restrict__ Out, int ldo,
    int K, int NB, int cpx)
{
  __shared__ unsigned short sA[2][128 * 32];
  __shared__ unsigned short sB[2][128 * 32];
  int id = blockIdx.x;
  int swz = (id & 7) * cpx + (id >> 3);
  int m0 = (swz / NB) * 128, n0 = (swz % NB) * 128;
  int tid = threadIdx.x, lane = tid & 63, wv = tid >> 6;
  int wm = wv >> 1, wn = wv & 1;

  f32x4 acc[4][4] = {};

  int idx0 = tid, idx1 = tid + 256;
  int r0 = idx0 >> 2, cg0 = (idx0 & 3) * 8;
  int r1 = idx1 >> 2, cg1 = (idx1 & 3) * 8;
  const unsigned short* Ab = A + (size_t)m0 * lda;
  const unsigned short* Bb = Bw + (size_t)n0 * ldb;

  int arow = wm * 64 + (lane & 15);
  int brow = wn * 64 + (lane & 15);
  int kk = (lane >> 4) * 8;

  int nt = K >> 5;
  // prologue: stage tile 0 into buf 0
  gll16(Ab + (size_t)r0 * lda + cg0, sA[0] + idx0 * 8);
  gll16(Ab + (size_t)r1 * lda + cg1, sA[0] + idx1 * 8);
  gll16(Bb + (size_t)r0 * ldb + cg0, sB[0] + idx0 * 8);
  gll16(Bb + (size_t)r1 * ldb + cg1, sB[0] + idx1 * 8);
  __syncthreads();

  int cur = 0;
  for (int t = 0; t < nt; ++t) {
    if (t + 1 < nt) {
      int kn = (t + 1) << 5;
      gll16(Ab + (size_t)r0 * lda + kn + cg0, sA[cur ^ 1] + idx0 * 8);
      gll16(Ab + (size_t)r1 * lda + kn + cg1, sA[cur ^ 1] + idx1 * 8);
      gll16(Bb + (size_t)r0 * ldb + kn + cg0, sB[cur ^ 1] + idx0 * 8);
      gll16(Bb + (size_t)r1 * ldb + kn + cg1, sB[cur ^ 1] + idx1 * 8);
    }
    __builtin_amdgcn_sched_barrier(0);   // keep prefetch issue ahead of compute
    const unsigned short* sAc = sA[cur];
    const unsigned short* sBc = sB[cur];
    bf16x8 af[4], bfr[4];
#pragma unroll
    for (int mi = 0; mi < 4; ++mi)
      af[mi] = *(const bf16x8*)(sAc + (arow + mi * 16) * 32 + kk);
#pragma unroll
    for (int ni = 0; ni < 4; ++ni)
      bfr[ni] = *(const bf16x8*)(sBc + (brow + ni * 16) * 32 + kk);
#pragma unroll
    for (int mi = 0; mi < 4; ++mi)
#pragma unroll
      for (int ni = 0; ni < 4; ++ni)
        acc[mi][ni] = __builtin_amdgcn_mfma_f32_16x16x32_bf16(af[mi], bfr[ni], acc[mi][ni], 0, 0, 0);
    __syncthreads();   // drains vmcnt(0): next tile ready; buffers swap-safe
    cur ^= 1;
  }

#pragma unroll
  for (int mi = 0; mi < 4; ++mi) {
    int rbase = m0 + wm * 64 + mi * 16 + (lane >> 4) * 4;
#pragma unroll
    for (int ni = 0; ni < 4; ++ni) {
      int col = n0 + wn * 64 + ni * 16 + (lane & 15);
      float bcol = bias[col];
#pragma unroll
      for (int r = 0; r < 4; ++r) {
        float v = acc[mi][ni][r] + bcol;
        v = 0.5f * v * (1.f + erff(v * 0.70710678118f));
        Out[(size_t)(rbase + r) * ldo + col] = f2bf(v);
      }
    }
  }
}

// ---------------- GEMM2 (half-K pass): Out = acc (+bias) + add ----------------
__global__ __launch_bounds__(256) void gemm_acc_kernel(
    const unsigned short* __restrict__ A, int lda,
    const unsigned short* __restrict__ Bw, int ldb,
    const float* __restrict__ bias,       // may be null
    const float* add, float* Out, int K, int NB, int cpx)
{
  __shared__ unsigned short sA[2][128 * 32];
  __shared__ unsigned short sB[2][128 * 32];
  int id = blockIdx.x;
  int swz = (id & 7) * cpx + (id >> 3);
  int m0 = (swz / NB) * 128, n0 = (swz % NB) * 128;
  int tid = threadIdx.x, lane = tid & 63, wv = tid >> 6;
  int wm = wv >> 1, wn = wv & 1;

  f32x4 acc[4][4] = {};

  int idx0 = tid, idx1 = tid + 256;
  int r0 = idx0 >> 2, cg0 = (idx0 & 3) * 8;
  int r1 = idx1 >> 2, cg1 = (idx1 & 3) * 8;
  const unsigned short* Ab = A + (size_t)m0 * lda;
  const unsigned short* Bb = Bw + (size_t)n0 * ldb;

  int arow = wm * 64 + (lane & 15);
  int brow = wn * 64 + (lane & 15);
  int kk = (lane >> 4) * 8;

  int nt = K >> 5;
  gll16(Ab + (size_t)r0 * lda + cg0, sA[0] + idx0 * 8);
  gll16(Ab + (size_t)r1 * lda + cg1, sA[0] + idx1 * 8);
  gll16(Bb + (size_t)r0 * ldb + cg0, sB[0] + idx0 * 8);
  gll16(Bb + (size_t)r1 * ldb + cg1, sB[0] + idx1 * 8);
  __syncthreads();

  int cur = 0;
  for (int t = 0; t < nt; ++t) {
    if (t + 1 < nt) {
      int kn = (t + 1) << 5;
      gll16(Ab + (size_t)r0 * lda + kn + cg0, sA[cur ^ 1] + idx0 * 8);
      gll16(Ab + (size_t)r1 * lda + kn + cg1, sA[cur ^ 1] + idx1 * 8);
      gll16(Bb + (size_t)r0 * ldb + kn + cg0, sB[cur ^ 1] + idx0 * 8);
      gll16(Bb + (size_t)r1 * ldb + kn + cg1, sB[cur ^ 1] + idx1 * 8);
    }
    __builtin_amdgcn_sched_barrier(0);
    const unsigned short* sAc = sA[cur];
    const unsigned short* sBc = sB[cur];
    bf16x8 af[4], bfr[4];
#pragma unroll
    for (int mi = 0; mi < 4; ++mi)
      af[mi] = *(const bf16x8*)(sAc + (arow + mi * 16) * 32 + kk);
#pragma unroll
    for (int ni = 0; ni < 4; ++ni)
      bfr[ni] = *(const bf16x8*)(sBc + (brow + ni * 16) * 32 + kk);
#pragma unroll
    for (int mi = 0; mi < 4; ++mi)
#pragma unroll
      for (int ni = 0; ni < 4; ++ni)
        acc[mi][ni] = __builtin_amdgcn_mfma_f32_16x16x32_bf16(af[mi], bfr[ni], acc[mi][ni], 0, 0, 0);
    __syncthreads();
    cur ^= 1;
  }

#pragma unroll
  for (int mi = 0; mi < 4; ++mi) {
    int rbase = m0 + wm * 64 + mi * 16 + (lane >> 4) * 4;
#pragma unroll
    for (int ni = 0; ni < 4; ++ni) {
      int col = n0 + wn * 64 + ni * 16 + (lane & 15);
      float bcol = bias ? bias[col] : 0.f;
#pragma unroll
      for (int r = 0; r < 4; ++r) {
        size_t off = (size_t)(rbase + r) * CC + col;
        Out[off] = acc[mi][ni][r] + bcol + add[off];
      }
    }
  }
}

// ---------------- launch ----------------
extern "C" void kernel_launch(void* const* d_in, const int* in_sizes, int n_in,
                              void* d_out, int out_size, void* d_ws, size_t ws_size,
                              hipStream_t stream)
{
  const float* x       = (const float*)d_in[0];
  const float* log_tau = (const float*)d_in[1];
  const float* log_dt  = (const float*)d_in[2];
  const float* mix     = (const float*)d_in[3];
  const float* Dv      = (const float*)d_in[4];
  const float* n1w     = (const float*)d_in[5];
  const float* n1b     = (const float*)d_in[6];
  const float* n2w     = (const float*)d_in[7];
  const float* n2b     = (const float*)d_in[8];
  const float* w1      = (const float*)d_in[9];
  const float* b1      = (const float*)d_in[10];
  const float* w2      = (const float*)d_in[11];
  const float* b2      = (const float*)d_in[12];

  // workspace layout (176 MB total)
  char* ws = (char*)d_ws;
  float* buf0 = (float*)ws;
  float* buf1 = (float*)(ws + (64ull << 20));
  unsigned short* a2  = (unsigned short*)(ws + (128ull << 20));
  unsigned short* w1b = (unsigned short*)(ws + (160ull << 20));
  unsigned short* w2b = (unsigned short*)(ws + (168ull << 20));
  unsigned short* act = (unsigned short*)buf0;   // alias: M x 2048 bf16 = 64 MB
  float* out = (float*)d_out;

  // 1. h = LN1(x)
  ln_f32_kernel<<<MM, 256, 0, stream>>>(x, n1w, n1b, buf0);
  // 2. hT = transpose(h)
  transpose_kernel<<<dim3(CC / 64, TT / 64, BB), 256, 0, stream>>>(buf0, buf1);
  // 3. y = s4d(hT)   (y -> buf0)
  s4d_kernel<<<BB * CC, 256, 0, stream>>>(buf1, log_tau, log_dt, mix, Dv, buf0);
  // 4. x2 = x + y^T  (x2 -> buf1)
  transadd_kernel<<<dim3(TT / 64, CC / 64, BB), 256, 0, stream>>>(buf0, x, buf1);
  // 5. a2 = bf16(LN2(x2))   (buf0/y now dead -> act aliases it)
  ln_bf16_kernel<<<MM, 256, 0, stream>>>(buf1, n2w, n2b, a2);
  // 6. weight casts
  cvt_bf16_kernel<<<(HH * CC / 4) / 256, 256, 0, stream>>>(w1, w1b);
  cvt_bf16_kernel<<<(HH * CC / 4) / 256, 256, 0, stream>>>(w2, w2b);

  // 7/8. MLP split along H into two halves of 2048 (act buffer = 64 MB)
  // half 0
  gemm_gelu_kernel<<<2048, 256, 0, stream>>>(
      a2, CC, w1b, CC, b1, act, 2048, CC, 16, 256);
  gemm_acc_kernel<<<1024, 256, 0, stream>>>(
      act, 2048, w2b, HH, b2, buf1, out, 2048, 8, 128);
  // half 1
  gemm_gelu_kernel<<<2048, 256, 0, stream>>>(
      a2, CC, w1b + (size_t)2048 * CC, CC, b1 + 2048, act, 2048, CC, 16, 256);
  gemm_acc_kernel<<<1024, 256, 0, stream>>>(
      act, 2048, w2b + 2048, HH, (const float*)nullptr, out, out, 2048, 8, 128);
}

// Round 7
// 746.964 us; speedup vs baseline: 1.4122x; 1.0891x over previous
//
#include <hip/hip_runtime.h>
#include <math.h>

// ---------------- common ----------------
typedef __attribute__((ext_vector_type(8))) short bf16x8;
typedef __attribute__((ext_vector_type(4))) float f32x4;

__device__ __forceinline__ unsigned short f2bf(float f) {
  union { float f; unsigned u; } v; v.f = f;
  unsigned r = v.u + 0x7fff + ((v.u >> 16) & 1);
  return (unsigned short)(r >> 16);
}

__device__ __forceinline__ float bf2f(unsigned short h) {
  union { unsigned u; float f; } v; v.u = ((unsigned)h) << 16;
  return v.f;
}

__device__ __forceinline__ void gll16(const void* g, void* l) {
  __builtin_amdgcn_global_load_lds(
      (const __attribute__((address_space(1))) void*)g,
      (__attribute__((address_space(3))) void*)l, 16, 0, 0);
}

#define BB 4
#define TT 4096
#define CC 1024
#define HH 4096
#define MM 16384   // B*T

// XOR swizzle for [rows][64 bf16] LDS tiles (row stride 128 B)
#define SWZ(row, byteoff) (((row) << 7) + ((byteoff) ^ (((row) & 7) << 4)))

// ---------------- LayerNorm (one block per row, C=1024) ----------------
__global__ __launch_bounds__(256) void ln_f32_kernel(
    const float* __restrict__ x, const float* __restrict__ w,
    const float* __restrict__ b, float* __restrict__ out)
{
  size_t row = blockIdx.x;
  const float4* xr = (const float4*)(x + row * CC);
  int tid = threadIdx.x;
  float4 v = xr[tid];
  float s = v.x + v.y + v.z + v.w;
  float sq = v.x*v.x + v.y*v.y + v.z*v.z + v.w*v.w;
  for (int o = 32; o; o >>= 1) { s += __shfl_xor(s, o); sq += __shfl_xor(sq, o); }
  __shared__ float ss[4], ssq[4];
  int wv = tid >> 6, lane = tid & 63;
  if (lane == 0) { ss[wv] = s; ssq[wv] = sq; }
  __syncthreads();
  s = ss[0] + ss[1] + ss[2] + ss[3];
  sq = ssq[0] + ssq[1] + ssq[2] + ssq[3];
  float mu = s * (1.f / CC);
  float var = sq * (1.f / CC) - mu * mu;
  float rstd = rsqrtf(var + 1e-5f);
  float4 wv4 = ((const float4*)w)[tid];
  float4 bv4 = ((const float4*)b)[tid];
  float4 o;
  o.x = (v.x - mu) * rstd * wv4.x + bv4.x;
  o.y = (v.y - mu) * rstd * wv4.y + bv4.y;
  o.z = (v.z - mu) * rstd * wv4.z + bv4.z;
  o.w = (v.w - mu) * rstd * wv4.w + bv4.w;
  ((float4*)(out + row * CC))[tid] = o;
}

__global__ __launch_bounds__(256) void ln_bf16_kernel(
    const float* __restrict__ x, const float* __restrict__ w,
    const float* __restrict__ b, unsigned short* __restrict__ out)
{
  size_t row = blockIdx.x;
  const float4* xr = (const float4*)(x + row * CC);
  int tid = threadIdx.x;
  float4 v = xr[tid];
  float s = v.x + v.y + v.z + v.w;
  float sq = v.x*v.x + v.y*v.y + v.z*v.z + v.w*v.w;
  for (int o = 32; o; o >>= 1) { s += __shfl_xor(s, o); sq += __shfl_xor(sq, o); }
  __shared__ float ss[4], ssq[4];
  int wv = tid >> 6, lane = tid & 63;
  if (lane == 0) { ss[wv] = s; ssq[wv] = sq; }
  __syncthreads();
  s = ss[0] + ss[1] + ss[2] + ss[3];
  sq = ssq[0] + ssq[1] + ssq[2] + ssq[3];
  float mu = s * (1.f / CC);
  float var = sq * (1.f / CC) - mu * mu;
  float rstd = rsqrtf(var + 1e-5f);
  float4 wv4 = ((const float4*)w)[tid];
  float4 bv4 = ((const float4*)b)[tid];
  ushort4 o;
  o.x = f2bf((v.x - mu) * rstd * wv4.x + bv4.x);
  o.y = f2bf((v.y - mu) * rstd * wv4.y + bv4.y);
  o.z = f2bf((v.z - mu) * rstd * wv4.z + bv4.z);
  o.w = f2bf((v.w - mu) * rstd * wv4.w + bv4.w);
  ((ushort4*)(out + row * CC))[tid] = o;
}

// ---------------- transpose h(B,T,C) -> hT(B,C,T) ----------------
__global__ __launch_bounds__(256) void transpose_kernel(
    const float* __restrict__ in, float* __restrict__ out)
{
  __shared__ float tile[64][65];
  size_t boff = (size_t)blockIdx.z * TT * CC;
  int r0 = blockIdx.y * 64;   // t dim
  int c0 = blockIdx.x * 64;   // c dim
  int tid = threadIdx.x;
#pragma unroll
  for (int i = 0; i < 16; ++i) {
    int idx = tid + i * 256;
    int r = idx >> 6, cx = idx & 63;
    tile[r][cx] = in[boff + (size_t)(r0 + r) * CC + c0 + cx];
  }
  __syncthreads();
#pragma unroll
  for (int i = 0; i < 16; ++i) {
    int idx = tid + i * 256;
    int r = idx >> 6, cx = idx & 63;
    out[boff + (size_t)(c0 + r) * TT + r0 + cx] = tile[cx][r];
  }
}

// ---------------- x2[b,t,c] = x[b,t,c] + y[b,c,t] ----------------
__global__ __launch_bounds__(256) void transadd_kernel(
    const float* __restrict__ y, const float* __restrict__ x,
    float* __restrict__ x2)
{
  __shared__ float tile[64][65];
  size_t boff = (size_t)blockIdx.z * TT * CC;
  int t0 = blockIdx.x * 64;
  int c0 = blockIdx.y * 64;
  int tid = threadIdx.x;
#pragma unroll
  for (int i = 0; i < 16; ++i) {
    int idx = tid + i * 256;
    int r = idx >> 6, cx = idx & 63;   // r: c-local, cx: t-local
    tile[r][cx] = y[boff + (size_t)(c0 + r) * TT + t0 + cx];
  }
  __syncthreads();
#pragma unroll
  for (int i = 0; i < 16; ++i) {
    int idx = tid + i * 256;
    int r = idx >> 6, cx = idx & 63;   // r: t-local, cx: c-local
    size_t off = boff + (size_t)(t0 + r) * CC + c0 + cx;
    x2[off] = x[off] + tile[cx][r];
  }
}

// ---------------- S4D via MFMA: one block per (b,c) row ----------------
__global__ __launch_bounds__(256) void s4d_kernel(
    const float* __restrict__ hT,      // (B, C, T)
    const float* __restrict__ log_tau, // (64)
    const float* __restrict__ log_dt,  // (1)
    const float* __restrict__ mix,     // (C, 64)
    const float* __restrict__ Dv,      // (C)
    float* __restrict__ y)             // (B, C, T)
{
  int bc = blockIdx.x;
  int c = bc & (CC - 1);
  int tid = threadIdx.x;
  int lane = tid & 63, w = tid >> 6;
  int m = lane & 15, g = lane >> 4;

  __shared__ unsigned short s_uh[64 * 64], s_ul[64 * 64];
  __shared__ unsigned short s_A2[64 * 64], s_Ac[64 * 64];
  __shared__ unsigned short s_T[64 * 64], s_Wt[64 * 64];
  __shared__ float s_P[64 * 64];
  __shared__ float s_a[64], s_rL[64], s_mix[64], s_K[64], s_Kp[4 * 64];

  // ---- stage u -> bf16 hi/lo (swizzled) ----
  const float4* urow = (const float4*)(hT + (size_t)bc * TT);
#pragma unroll
  for (int q = 0; q < 4; ++q) {
    int i = tid + q * 256;           // float4 index in row
    float4 v = urow[i];
    int row = i >> 4;                // chunk index k
    int colb = (i & 15) * 8;         // byte offset of s within row
    float f[4] = {v.x, v.y, v.z, v.w};
    ushort4 hh, ll;
    unsigned short* hp = (unsigned short*)&hh;
    unsigned short* lp = (unsigned short*)&ll;
#pragma unroll
    for (int r = 0; r < 4; ++r) {
      unsigned short hb = f2bf(f[r]);
      hp[r] = hb;
      lp[r] = f2bf(f[r] - bf2f(hb));
    }
    *(ushort4*)((char*)s_uh + SWZ(row, colb)) = hh;
    *(ushort4*)((char*)s_ul + SWZ(row, colb)) = ll;
  }
  if (tid < 64) {
    float lt = log_tau[tid];
    float tau = (lt > 20.f) ? lt : log1pf(expf(lt));
    float ld = log_dt[0];
    float dt = (ld > 20.f) ? ld : log1pf(expf(ld));
    float a = tau * dt;
    s_a[tid] = a;
    s_rL[tid] = expf(-64.f * a);
    s_mix[tid] = mix[c * 64 + tid];
  }
  __syncthreads();   // (1) u, params ready

  // ---- build A2, Ac ----
#pragma unroll
  for (int e = 0; e < 16; ++e) {
    int idx = tid + e * 256;
    int rA = idx >> 6, cA = idx & 63;
    s_A2[SWZ(rA, cA * 2) >> 1] = f2bf(expf(-s_a[rA] * (float)(63 - cA)));
    s_Ac[SWZ(rA, cA * 2) >> 1] = f2bf(expf(-s_a[cA] * (float)(rA + 1)));
  }
  __syncthreads();   // (2) A2/Ac ready

  // ---- K partials ----
  {
    int d = tid & 63, q = tid >> 6;
    float p = 0.f;
    if (d == 0) {
#pragma unroll
      for (int j = 16 * q; j < 16 * q + 16; ++j) p += s_mix[j];
    } else {
#pragma unroll
      for (int j = 16 * q; j < 16 * q + 16; ++j)
        p = fmaf(s_mix[j], bf2f(s_Ac[SWZ(d - 1, j * 2) >> 1]), p);
    }
    s_Kp[q * 64 + d] = p;
  }

  // ---- phase 1: P = A2 @ (Uh + Ul) ----
  {
    f32x4 accP[4] = {};
    bf16x8 a2f[2];
#pragma unroll
    for (int ks = 0; ks < 2; ++ks)
      a2f[ks] = *(const bf16x8*)((const char*)s_A2 + SWZ(16 * w + m, ks * 64 + g * 16));
#pragma unroll
    for (int ct = 0; ct < 4; ++ct) {
#pragma unroll
      for (int ks = 0; ks < 2; ++ks) {
        bf16x8 bh = *(const bf16x8*)((const char*)s_uh + SWZ(ct * 16 + m, ks * 64 + g * 16));
        bf16x8 bl = *(const bf16x8*)((const char*)s_ul + SWZ(ct * 16 + m, ks * 64 + g * 16));
        accP[ct] = __builtin_amdgcn_mfma_f32_16x16x32_bf16(a2f[ks], bh, accP[ct], 0, 0, 0);
        accP[ct] = __builtin_amdgcn_mfma_f32_16x16x32_bf16(a2f[ks], bl, accP[ct], 0, 0, 0);
      }
    }
#pragma unroll
    for (int ct = 0; ct < 4; ++ct)
      *(f32x4*)&s_P[(ct * 16 + m) * 64 + 16 * w + g * 4] = accP[ct];
  }
  __syncthreads();   // (3) Kp + P ready

  if (tid < 64)
    s_K[tid] = s_Kp[tid] + s_Kp[64 + tid] + s_Kp[128 + tid] + s_Kp[192 + tid];
  __syncthreads();   // (4) K ready

  // ---- build T[t][s] = K[t-s] for s<=t ----
#pragma unroll
  for (int e = 0; e < 16; ++e) {
    int idx = tid + e * 256;
    int t = idx >> 6, s = idx & 63;
    float val = (s <= t) ? s_K[t - s] : 0.f;
    s_T[SWZ(t, s * 2) >> 1] = f2bf(val);
  }
  // ---- scan (lane j): W[j][k] = mix_j * S_before[k], stored Wt[k][j] ----
  if (tid < 64) {
    int j = tid;
    float S = 0.f, rL = s_rL[j], mj = s_mix[j];
    for (int k = 0; k < 64; ++k) {
      s_Wt[SWZ(k, j * 2) >> 1] = f2bf(mj * S);
      S = fmaf(rL, S, s_P[k * 64 + j]);
    }
  }
  __syncthreads();   // (5) T + Wt ready

  // ---- phase 2: Y = Ac @ W + T @ (Uh + Ul) ----
  f32x4 accY[4] = {};
  {
    bf16x8 acf[2], tf[2];
#pragma unroll
    for (int ks = 0; ks < 2; ++ks) {
      acf[ks] = *(const bf16x8*)((const char*)s_Ac + SWZ(16 * w + m, ks * 64 + g * 16));
      tf[ks]  = *(const bf16x8*)((const char*)s_T  + SWZ(16 * w + m, ks * 64 + g * 16));
    }
#pragma unroll
    for (int ct = 0; ct < 4; ++ct) {
#pragma unroll
      for (int ks = 0; ks < 2; ++ks) {
        bf16x8 bw  = *(const bf16x8*)((const char*)s_Wt + SWZ(ct * 16 + m, ks * 64 + g * 16));
        bf16x8 uhf = *(const bf16x8*)((const char*)s_uh + SWZ(ct * 16 + m, ks * 64 + g * 16));
        bf16x8 ulf = *(const bf16x8*)((const char*)s_ul + SWZ(ct * 16 + m, ks * 64 + g * 16));
        accY[ct] = __builtin_amdgcn_mfma_f32_16x16x32_bf16(acf[ks], bw,  accY[ct], 0, 0, 0);
        accY[ct] = __builtin_amdgcn_mfma_f32_16x16x32_bf16(tf[ks],  uhf, accY[ct], 0, 0, 0);
        accY[ct] = __builtin_amdgcn_mfma_f32_16x16x32_bf16(tf[ks],  ulf, accY[ct], 0, 0, 0);
      }
    }
  }

  // ---- epilogue: y[k*64+t] = Y[t][k] + D_c * u ----
  float Dc = Dv[c];
  float* yrow = y + (size_t)bc * TT;
#pragma unroll
  for (int ct = 0; ct < 4; ++ct) {
    int k = ct * 16 + m;
    int t0 = 16 * w + g * 4;
    float4 o;
    float* op = (float*)&o;
#pragma unroll
    for (int r = 0; r < 4; ++r) {
      int t = t0 + r;
      float uf = bf2f(s_uh[SWZ(k, t * 2) >> 1]) + bf2f(s_ul[SWZ(k, t * 2) >> 1]);
      op[r] = accY[ct][r] + Dc * uf;
    }
    *(float4*)(yrow + k * 64 + t0) = o;
  }
}

// ---------------- f32 -> bf16 convert ----------------
__global__ __launch_bounds__(256) void cvt_bf16_kernel(
    const float* __restrict__ in, unsigned short* __restrict__ out)
{
  int i = blockIdx.x * 256 + threadIdx.x;
  float4 v = ((const float4*)in)[i];
  ushort4 o;
  o.x = f2bf(v.x); o.y = f2bf(v.y); o.z = f2bf(v.z); o.w = f2bf(v.w);
  ((ushort4*)out)[i] = o;
}

// =====================================================================
// 256x256-tile GEMM, BK=64, 512 threads (8 waves, 2Mx4N), 2-deep pipeline
// with counted vmcnt (raw s_barrier; never vmcnt(0) in steady state).
// LDS 128 KB: sA/sB double-buffered [256][64] bf16, XOR-swizzled via
// pre-swizzled global source (linear gll dest) + SWZ on ds_read.
// =====================================================================

// common prologue/loop as macro to keep both epilogue variants in sync
#define GEMM256_BODY(A_, lda_, B_, ldb_, K_)                                   \
  __shared__ unsigned short sA[2][256 * 64];                                   \
  __shared__ unsigned short sB[2][256 * 64];                                   \
  int id = blockIdx.x;                                                         \
  int swz = (id & 7) * cpx + (id >> 3);                                        \
  int m0 = (swz / NB) * 256, n0 = (swz % NB) * 256;                            \
  int tid = threadIdx.x, lane = tid & 63;                                      \
  int wid = tid >> 6, wm = wid >> 2, wn = wid & 3;                             \
  int m = lane & 15, g = lane >> 4;                                            \
  const unsigned short* aSrc[4];                                               \
  const unsigned short* bSrc[4];                                               \
  int ldsOff[4];                                                               \
  _Pragma("unroll")                                                            \
  for (int i = 0; i < 4; ++i) {                                                \
    int j = i * 512 + tid;                                                     \
    int row = j >> 3;                                                          \
    int colb = ((j & 7) * 16) ^ ((row & 7) << 4);                              \
    aSrc[i] = (A_) + (size_t)(m0 + row) * (lda_) + (colb >> 1);                \
    bSrc[i] = (B_) + (size_t)(n0 + row) * (ldb_) + (colb >> 1);                \
    ldsOff[i] = j * 8;                                                         \
  }                                                                            \
  f32x4 acc[8][4] = {};                                                        \
  int nt = (K_) >> 6;                                                          \
  /* prologue: stage tiles 0,1 */                                              \
  _Pragma("unroll")                                                            \
  for (int i = 0; i < 4; ++i) gll16(aSrc[i], &sA[0][ldsOff[i]]);               \
  _Pragma("unroll")                                                            \
  for (int i = 0; i < 4; ++i) gll16(bSrc[i], &sB[0][ldsOff[i]]);               \
  _Pragma("unroll")                                                            \
  for (int i = 0; i < 4; ++i) gll16(aSrc[i] + 64, &sA[1][ldsOff[i]]);          \
  _Pragma("unroll")                                                            \
  for (int i = 0; i < 4; ++i) gll16(bSrc[i] + 64, &sB[1][ldsOff[i]]);          \
  asm volatile("s_waitcnt vmcnt(8)" ::: "memory");                             \
  asm volatile("s_barrier" ::: "memory");                                      \
  int cur = 0;                                                                 \
  for (int kt = 0; kt < nt; ++kt) {                                            \
    const unsigned short* sAc = sA[cur];                                       \
    const unsigned short* sBc = sB[cur];                                       \
    bf16x8 bfr[4][2];                                                          \
    _Pragma("unroll")                                                          \
    for (int ni = 0; ni < 4; ++ni)                                             \
      _Pragma("unroll")                                                        \
      for (int ks = 0; ks < 2; ++ks)                                           \
        bfr[ni][ks] = *(const bf16x8*)((const char*)sBc +                      \
                        SWZ(wn * 64 + ni * 16 + m, ks * 64 + g * 16));         \
    _Pragma("unroll")                                                          \
    for (int q = 0; q < 4; ++q) {                                              \
      bf16x8 af[2][2];                                                         \
      _Pragma("unroll")                                                        \
      for (int mi = 0; mi < 2; ++mi)                                           \
        _Pragma("unroll")                                                      \
        for (int ks = 0; ks < 2; ++ks)                                         \
          af[mi][ks] = *(const bf16x8*)((const char*)sAc +                     \
                         SWZ(wm * 128 + (q * 2 + mi) * 16 + m,                 \
                             ks * 64 + g * 16));                               \
      __builtin_amdgcn_s_setprio(1);                                           \
      _Pragma("unroll")                                                        \
      for (int mi = 0; mi < 2; ++mi)                                           \
        _Pragma("unroll")                                                      \
        for (int ni = 0; ni < 4; ++ni) {                                       \
          acc[q * 2 + mi][ni] = __builtin_amdgcn_mfma_f32_16x16x32_bf16(       \
              af[mi][0], bfr[ni][0], acc[q * 2 + mi][ni], 0, 0, 0);            \
          acc[q * 2 + mi][ni] = __builtin_amdgcn_mfma_f32_16x16x32_bf16(       \
              af[mi][1], bfr[ni][1], acc[q * 2 + mi][ni], 0, 0, 0);            \
        }                                                                      \
      __builtin_amdgcn_s_setprio(0);                                           \
    }                                                                          \
    if (kt + 1 < nt) {                                                         \
      asm volatile("s_barrier" ::: "memory"); /* all done reading buf[cur] */  \
      if (kt + 2 < nt) {                                                       \
        int ko = (kt + 2) << 6;                                                \
        _Pragma("unroll")                                                      \
        for (int i = 0; i < 4; ++i) gll16(aSrc[i] + ko, &sA[cur][ldsOff[i]]);  \
        _Pragma("unroll")                                                      \
        for (int i = 0; i < 4; ++i) gll16(bSrc[i] + ko, &sB[cur][ldsOff[i]]);  \
        asm volatile("s_waitcnt vmcnt(8)" ::: "memory");                       \
      } else {                                                                 \
        asm volatile("s_waitcnt vmcnt(0)" ::: "memory");                       \
      }                                                                        \
      asm volatile("s_barrier" ::: "memory"); /* buf[cur^1] staged+visible */  \
      cur ^= 1;                                                                \
    }                                                                          \
  }

// ---------------- GEMM1 (half-H): act = gelu(A @ Bw^T + bias), bf16 out ----
__global__ __launch_bounds__(512, 2) void gemm_gelu_kernel(
    const unsigned short* __restrict__ A, int lda,
    const unsigned short* __restrict__ Bw, int ldb,
    const float* __restrict__ bias, unsigned short* __restrict__ Out, int ldo,
    int K, int NB, int cpx)
{
  GEMM256_BODY(A, lda, Bw, ldb, K)

#pragma unroll
  for (int mi = 0; mi < 8; ++mi) {
    int row = m0 + wm * 128 + mi * 16 + g * 4;
#pragma unroll
    for (int ni = 0; ni < 4; ++ni) {
      int col = n0 + wn * 64 + ni * 16 + m;
      float bcol = bias[col];
#pragma unroll
      for (int r = 0; r < 4; ++r) {
        float v = acc[mi][ni][r] + bcol;
        v = 0.5f * v * (1.f + erff(v * 0.70710678118f));
        Out[(size_t)(row + r) * ldo + col] = f2bf(v);
      }
    }
  }
}

// ---------------- GEMM2 (half-K pass): Out = acc (+bias) + add -------------
__global__ __launch_bounds__(512, 2) void gemm_acc_kernel(
    const unsigned short* __restrict__ A, int lda,
    const unsigned short* __restrict__ Bw, int ldb,
    const float* __restrict__ bias,       // may be null
    const float* add, float* Out, int K, int NB, int cpx)
{
  GEMM256_BODY(A, lda, Bw, ldb, K)

#pragma unroll
  for (int mi = 0; mi < 8; ++mi) {
    int row = m0 + wm * 128 + mi * 16 + g * 4;
#pragma unroll
    for (int ni = 0; ni < 4; ++ni) {
      int col = n0 + wn * 64 + ni * 16 + m;
      float bcol = bias ? bias[col] : 0.f;
#pragma unroll
      for (int r = 0; r < 4; ++r) {
        size_t off = (size_t)(row + r) * CC + col;
        Out[off] = acc[mi][ni][r] + bcol + add[off];
      }
    }
  }
}

// ---------------- launch ----------------
extern "C" void kernel_launch(void* const* d_in, const int* in_sizes, int n_in,
                              void* d_out, int out_size, void* d_ws, size_t ws_size,
                              hipStream_t stream)
{
  const float* x       = (const float*)d_in[0];
  const float* log_tau = (const float*)d_in[1];
  const float* log_dt  = (const float*)d_in[2];
  const float* mix     = (const float*)d_in[3];
  const float* Dv      = (const float*)d_in[4];
  const float* n1w     = (const float*)d_in[5];
  const float* n1b     = (const float*)d_in[6];
  const float* n2w     = (const float*)d_in[7];
  const float* n2b     = (const float*)d_in[8];
  const float* w1      = (const float*)d_in[9];
  const float* b1      = (const float*)d_in[10];
  const float* w2      = (const float*)d_in[11];
  const float* b2      = (const float*)d_in[12];

  // workspace layout (176 MB total)
  char* ws = (char*)d_ws;
  float* buf0 = (float*)ws;
  float* buf1 = (float*)(ws + (64ull << 20));
  unsigned short* a2  = (unsigned short*)(ws + (128ull << 20));
  unsigned short* w1b = (unsigned short*)(ws + (160ull << 20));
  unsigned short* w2b = (unsigned short*)(ws + (168ull << 20));
  unsigned short* act = (unsigned short*)buf0;   // alias: M x 2048 bf16 = 64 MB
  float* out = (float*)d_out;

  // 1. h = LN1(x)
  ln_f32_kernel<<<MM, 256, 0, stream>>>(x, n1w, n1b, buf0);
  // 2. hT = transpose(h)
  transpose_kernel<<<dim3(CC / 64, TT / 64, BB), 256, 0, stream>>>(buf0, buf1);
  // 3. y = s4d(hT)   (y -> buf0)
  s4d_kernel<<<BB * CC, 256, 0, stream>>>(buf1, log_tau, log_dt, mix, Dv, buf0);
  // 4. x2 = x + y^T  (x2 -> buf1)
  transadd_kernel<<<dim3(TT / 64, CC / 64, BB), 256, 0, stream>>>(buf0, x, buf1);
  // 5. a2 = bf16(LN2(x2))   (buf0/y now dead -> act aliases it)
  ln_bf16_kernel<<<MM, 256, 0, stream>>>(buf1, n2w, n2b, a2);
  // 6. weight casts
  cvt_bf16_kernel<<<(HH * CC / 4) / 256, 256, 0, stream>>>(w1, w1b);
  cvt_bf16_kernel<<<(HH * CC / 4) / 256, 256, 0, stream>>>(w2, w2b);

  // 7/8. MLP split along H into two halves of 2048 (act buffer = 64 MB)
  // gemm_gelu: grid 64x8=512, NB=8, cpx=64, K=1024
  // gemm_acc:  grid 64x4=256, NB=4, cpx=32, K=2048
  // half 0
  gemm_gelu_kernel<<<512, 512, 0, stream>>>(
      a2, CC, w1b, CC, b1, act, 2048, CC, 8, 64);
  gemm_acc_kernel<<<256, 512, 0, stream>>>(
      act, 2048, w2b, HH, b2, buf1, out, 2048, 4, 32);
  // half 1
  gemm_gelu_kernel<<<512, 512, 0, stream>>>(
      a2, CC, w1b + (size_t)2048 * CC, CC, b1 + 2048, act, 2048, CC, 8, 64);
  gemm_acc_kernel<<<256, 512, 0, stream>>>(
      act, 2048, w2b + 2048, HH, (const float*)nullptr, out, out, 2048, 4, 32);
}

// Round 8
// 732.142 us; speedup vs baseline: 1.4407x; 1.0202x over previous
//
#include <hip/hip_runtime.h>
#include <math.h>

// ---------------- common ----------------
typedef __attribute__((ext_vector_type(8))) short bf16x8;
typedef __attribute__((ext_vector_type(4))) float f32x4;

__device__ __forceinline__ unsigned short f2bf(float f) {
  union { float f; unsigned u; } v; v.f = f;
  unsigned r = v.u + 0x7fff + ((v.u >> 16) & 1);
  return (unsigned short)(r >> 16);
}

__device__ __forceinline__ float bf2f(unsigned short h) {
  union { unsigned u; float f; } v; v.u = ((unsigned)h) << 16;
  return v.f;
}

__device__ __forceinline__ void gll16(const void* g, void* l) {
  __builtin_amdgcn_global_load_lds(
      (const __attribute__((address_space(1))) void*)g,
      (__attribute__((address_space(3))) void*)l, 16, 0, 0);
}

#define BB 4
#define TT 4096
#define CC 1024
#define HH 4096
#define MM 16384   // B*T

// XOR swizzle for [rows][64 bf16] LDS tiles (row stride 128 B)
#define SWZ(row, byteoff) (((row) << 7) + ((byteoff) ^ (((row) & 7) << 4)))

// ---------------- LayerNorm (one block per row, C=1024) ----------------
__global__ __launch_bounds__(256) void ln_f32_kernel(
    const float* __restrict__ x, const float* __restrict__ w,
    const float* __restrict__ b, float* __restrict__ out)
{
  size_t row = blockIdx.x;
  const float4* xr = (const float4*)(x + row * CC);
  int tid = threadIdx.x;
  float4 v = xr[tid];
  float s = v.x + v.y + v.z + v.w;
  float sq = v.x*v.x + v.y*v.y + v.z*v.z + v.w*v.w;
  for (int o = 32; o; o >>= 1) { s += __shfl_xor(s, o); sq += __shfl_xor(sq, o); }
  __shared__ float ss[4], ssq[4];
  int wv = tid >> 6, lane = tid & 63;
  if (lane == 0) { ss[wv] = s; ssq[wv] = sq; }
  __syncthreads();
  s = ss[0] + ss[1] + ss[2] + ss[3];
  sq = ssq[0] + ssq[1] + ssq[2] + ssq[3];
  float mu = s * (1.f / CC);
  float var = sq * (1.f / CC) - mu * mu;
  float rstd = rsqrtf(var + 1e-5f);
  float4 wv4 = ((const float4*)w)[tid];
  float4 bv4 = ((const float4*)b)[tid];
  float4 o;
  o.x = (v.x - mu) * rstd * wv4.x + bv4.x;
  o.y = (v.y - mu) * rstd * wv4.y + bv4.y;
  o.z = (v.z - mu) * rstd * wv4.z + bv4.z;
  o.w = (v.w - mu) * rstd * wv4.w + bv4.w;
  ((float4*)(out + row * CC))[tid] = o;
}

__global__ __launch_bounds__(256) void ln_bf16_kernel(
    const float* __restrict__ x, const float* __restrict__ w,
    const float* __restrict__ b, unsigned short* __restrict__ out)
{
  size_t row = blockIdx.x;
  const float4* xr = (const float4*)(x + row * CC);
  int tid = threadIdx.x;
  float4 v = xr[tid];
  float s = v.x + v.y + v.z + v.w;
  float sq = v.x*v.x + v.y*v.y + v.z*v.z + v.w*v.w;
  for (int o = 32; o; o >>= 1) { s += __shfl_xor(s, o); sq += __shfl_xor(sq, o); }
  __shared__ float ss[4], ssq[4];
  int wv = tid >> 6, lane = tid & 63;
  if (lane == 0) { ss[wv] = s; ssq[wv] = sq; }
  __syncthreads();
  s = ss[0] + ss[1] + ss[2] + ss[3];
  sq = ssq[0] + ssq[1] + ssq[2] + ssq[3];
  float mu = s * (1.f / CC);
  float var = sq * (1.f / CC) - mu * mu;
  float rstd = rsqrtf(var + 1e-5f);
  float4 wv4 = ((const float4*)w)[tid];
  float4 bv4 = ((const float4*)b)[tid];
  ushort4 o;
  o.x = f2bf((v.x - mu) * rstd * wv4.x + bv4.x);
  o.y = f2bf((v.y - mu) * rstd * wv4.y + bv4.y);
  o.z = f2bf((v.z - mu) * rstd * wv4.z + bv4.z);
  o.w = f2bf((v.w - mu) * rstd * wv4.w + bv4.w);
  ((ushort4*)(out + row * CC))[tid] = o;
}

// ---------------- transpose h(B,T,C) -> hT(B,C,T) ----------------
__global__ __launch_bounds__(256) void transpose_kernel(
    const float* __restrict__ in, float* __restrict__ out)
{
  __shared__ float tile[64][65];
  size_t boff = (size_t)blockIdx.z * TT * CC;
  int r0 = blockIdx.y * 64;   // t dim
  int c0 = blockIdx.x * 64;   // c dim
  int tid = threadIdx.x;
#pragma unroll
  for (int i = 0; i < 16; ++i) {
    int idx = tid + i * 256;
    int r = idx >> 6, cx = idx & 63;
    tile[r][cx] = in[boff + (size_t)(r0 + r) * CC + c0 + cx];
  }
  __syncthreads();
#pragma unroll
  for (int i = 0; i < 16; ++i) {
    int idx = tid + i * 256;
    int r = idx >> 6, cx = idx & 63;
    out[boff + (size_t)(c0 + r) * TT + r0 + cx] = tile[cx][r];
  }
}

// ---------------- x2[b,t,c] = x[b,t,c] + y[b,c,t] ----------------
__global__ __launch_bounds__(256) void transadd_kernel(
    const float* __restrict__ y, const float* __restrict__ x,
    float* __restrict__ x2)
{
  __shared__ float tile[64][65];
  size_t boff = (size_t)blockIdx.z * TT * CC;
  int t0 = blockIdx.x * 64;
  int c0 = blockIdx.y * 64;
  int tid = threadIdx.x;
#pragma unroll
  for (int i = 0; i < 16; ++i) {
    int idx = tid + i * 256;
    int r = idx >> 6, cx = idx & 63;   // r: c-local, cx: t-local
    tile[r][cx] = y[boff + (size_t)(c0 + r) * TT + t0 + cx];
  }
  __syncthreads();
#pragma unroll
  for (int i = 0; i < 16; ++i) {
    int idx = tid + i * 256;
    int r = idx >> 6, cx = idx & 63;   // r: t-local, cx: c-local
    size_t off = boff + (size_t)(t0 + r) * CC + c0 + cx;
    x2[off] = x[off] + tile[cx][r];
  }
}

// ---------------- S4D via MFMA: one block per (b,c) row ----------------
__global__ __launch_bounds__(256) void s4d_kernel(
    const float* __restrict__ hT,      // (B, C, T)
    const float* __restrict__ log_tau, // (64)
    const float* __restrict__ log_dt,  // (1)
    const float* __restrict__ mix,     // (C, 64)
    const float* __restrict__ Dv,      // (C)
    float* __restrict__ y)             // (B, C, T)
{
  int bc = blockIdx.x;
  int c = bc & (CC - 1);
  int tid = threadIdx.x;
  int lane = tid & 63, w = tid >> 6;
  int m = lane & 15, g = lane >> 4;

  __shared__ unsigned short s_uh[64 * 64], s_ul[64 * 64];
  __shared__ unsigned short s_A2[64 * 64], s_Ac[64 * 64];
  __shared__ unsigned short s_T[64 * 64], s_Wt[64 * 64];
  __shared__ float s_P[64 * 64];
  __shared__ float s_a[64], s_rL[64], s_mix[64], s_K[64], s_Kp[4 * 64];

  // ---- stage u -> bf16 hi/lo (swizzled) ----
  const float4* urow = (const float4*)(hT + (size_t)bc * TT);
#pragma unroll
  for (int q = 0; q < 4; ++q) {
    int i = tid + q * 256;           // float4 index in row
    float4 v = urow[i];
    int row = i >> 4;                // chunk index k
    int colb = (i & 15) * 8;         // byte offset of s within row
    float f[4] = {v.x, v.y, v.z, v.w};
    ushort4 hh, ll;
    unsigned short* hp = (unsigned short*)&hh;
    unsigned short* lp = (unsigned short*)&ll;
#pragma unroll
    for (int r = 0; r < 4; ++r) {
      unsigned short hb = f2bf(f[r]);
      hp[r] = hb;
      lp[r] = f2bf(f[r] - bf2f(hb));
    }
    *(ushort4*)((char*)s_uh + SWZ(row, colb)) = hh;
    *(ushort4*)((char*)s_ul + SWZ(row, colb)) = ll;
  }
  if (tid < 64) {
    float lt = log_tau[tid];
    float tau = (lt > 20.f) ? lt : log1pf(expf(lt));
    float ld = log_dt[0];
    float dt = (ld > 20.f) ? ld : log1pf(expf(ld));
    float a = tau * dt;
    s_a[tid] = a;
    s_rL[tid] = expf(-64.f * a);
    s_mix[tid] = mix[c * 64 + tid];
  }
  __syncthreads();   // (1) u, params ready

  // ---- build A2, Ac ----
#pragma unroll
  for (int e = 0; e < 16; ++e) {
    int idx = tid + e * 256;
    int rA = idx >> 6, cA = idx & 63;
    s_A2[SWZ(rA, cA * 2) >> 1] = f2bf(expf(-s_a[rA] * (float)(63 - cA)));
    s_Ac[SWZ(rA, cA * 2) >> 1] = f2bf(expf(-s_a[cA] * (float)(rA + 1)));
  }
  __syncthreads();   // (2) A2/Ac ready

  // ---- K partials ----
  {
    int d = tid & 63, q = tid >> 6;
    float p = 0.f;
    if (d == 0) {
#pragma unroll
      for (int j = 16 * q; j < 16 * q + 16; ++j) p += s_mix[j];
    } else {
#pragma unroll
      for (int j = 16 * q; j < 16 * q + 16; ++j)
        p = fmaf(s_mix[j], bf2f(s_Ac[SWZ(d - 1, j * 2) >> 1]), p);
    }
    s_Kp[q * 64 + d] = p;
  }

  // ---- phase 1: P = A2 @ (Uh + Ul) ----
  {
    f32x4 accP[4] = {};
    bf16x8 a2f[2];
#pragma unroll
    for (int ks = 0; ks < 2; ++ks)
      a2f[ks] = *(const bf16x8*)((const char*)s_A2 + SWZ(16 * w + m, ks * 64 + g * 16));
#pragma unroll
    for (int ct = 0; ct < 4; ++ct) {
#pragma unroll
      for (int ks = 0; ks < 2; ++ks) {
        bf16x8 bh = *(const bf16x8*)((const char*)s_uh + SWZ(ct * 16 + m, ks * 64 + g * 16));
        bf16x8 bl = *(const bf16x8*)((const char*)s_ul + SWZ(ct * 16 + m, ks * 64 + g * 16));
        accP[ct] = __builtin_amdgcn_mfma_f32_16x16x32_bf16(a2f[ks], bh, accP[ct], 0, 0, 0);
        accP[ct] = __builtin_amdgcn_mfma_f32_16x16x32_bf16(a2f[ks], bl, accP[ct], 0, 0, 0);
      }
    }
#pragma unroll
    for (int ct = 0; ct < 4; ++ct)
      *(f32x4*)&s_P[(ct * 16 + m) * 64 + 16 * w + g * 4] = accP[ct];
  }
  __syncthreads();   // (3) Kp + P ready

  if (tid < 64)
    s_K[tid] = s_Kp[tid] + s_Kp[64 + tid] + s_Kp[128 + tid] + s_Kp[192 + tid];
  __syncthreads();   // (4) K ready

  // ---- build T[t][s] = K[t-s] for s<=t ----
#pragma unroll
  for (int e = 0; e < 16; ++e) {
    int idx = tid + e * 256;
    int t = idx >> 6, s = idx & 63;
    float val = (s <= t) ? s_K[t - s] : 0.f;
    s_T[SWZ(t, s * 2) >> 1] = f2bf(val);
  }
  // ---- scan (lane j): W[j][k] = mix_j * S_before[k], stored Wt[k][j] ----
  if (tid < 64) {
    int j = tid;
    float S = 0.f, rL = s_rL[j], mj = s_mix[j];
    for (int k = 0; k < 64; ++k) {
      s_Wt[SWZ(k, j * 2) >> 1] = f2bf(mj * S);
      S = fmaf(rL, S, s_P[k * 64 + j]);
    }
  }
  __syncthreads();   // (5) T + Wt ready

  // ---- phase 2: Y = Ac @ W + T @ (Uh + Ul) ----
  f32x4 accY[4] = {};
  {
    bf16x8 acf[2], tf[2];
#pragma unroll
    for (int ks = 0; ks < 2; ++ks) {
      acf[ks] = *(const bf16x8*)((const char*)s_Ac + SWZ(16 * w + m, ks * 64 + g * 16));
      tf[ks]  = *(const bf16x8*)((const char*)s_T  + SWZ(16 * w + m, ks * 64 + g * 16));
    }
#pragma unroll
    for (int ct = 0; ct < 4; ++ct) {
#pragma unroll
      for (int ks = 0; ks < 2; ++ks) {
        bf16x8 bw  = *(const bf16x8*)((const char*)s_Wt + SWZ(ct * 16 + m, ks * 64 + g * 16));
        bf16x8 uhf = *(const bf16x8*)((const char*)s_uh + SWZ(ct * 16 + m, ks * 64 + g * 16));
        bf16x8 ulf = *(const bf16x8*)((const char*)s_ul + SWZ(ct * 16 + m, ks * 64 + g * 16));
        accY[ct] = __builtin_amdgcn_mfma_f32_16x16x32_bf16(acf[ks], bw,  accY[ct], 0, 0, 0);
        accY[ct] = __builtin_amdgcn_mfma_f32_16x16x32_bf16(tf[ks],  uhf, accY[ct], 0, 0, 0);
        accY[ct] = __builtin_amdgcn_mfma_f32_16x16x32_bf16(tf[ks],  ulf, accY[ct], 0, 0, 0);
      }
    }
  }

  // ---- epilogue: y[k*64+t] = Y[t][k] + D_c * u ----
  float Dc = Dv[c];
  float* yrow = y + (size_t)bc * TT;
#pragma unroll
  for (int ct = 0; ct < 4; ++ct) {
    int k = ct * 16 + m;
    int t0 = 16 * w + g * 4;
    float4 o;
    float* op = (float*)&o;
#pragma unroll
    for (int r = 0; r < 4; ++r) {
      int t = t0 + r;
      float uf = bf2f(s_uh[SWZ(k, t * 2) >> 1]) + bf2f(s_ul[SWZ(k, t * 2) >> 1]);
      op[r] = accY[ct][r] + Dc * uf;
    }
    *(float4*)(yrow + k * 64 + t0) = o;
  }
}

// ---------------- f32 -> bf16 convert ----------------
__global__ __launch_bounds__(256) void cvt_bf16_kernel(
    const float* __restrict__ in, unsigned short* __restrict__ out)
{
  int i = blockIdx.x * 256 + threadIdx.x;
  float4 v = ((const float4*)in)[i];
  ushort4 o;
  o.x = f2bf(v.x); o.y = f2bf(v.y); o.z = f2bf(v.z); o.w = f2bf(v.w);
  ((ushort4*)out)[i] = o;
}

// =====================================================================
// 256x256 GEMM, BK=64, 512 thr (8 waves 2Mx4N), 4-phase fine interleave.
// Per K-tile kt (buf cur=kt&1), phase q computes output quadrant q and
// stages chunks of tile kt+2 into regions of buf[cur] that died at an
// earlier phase barrier:
//   B[cur] read entirely in phase 0 (bfr)         -> stage B(kt+2) ph1/ph2
//   A-slice q (rows wm*128+q*32..+31) read ph q   -> stage A-s0 ph2,
//     A-s1/A-s2 ph3, A-s3 deferred to NEXT tile's ph0 (into buf[cur^1])
// vmcnt(7) once per tile at ph0 = wait own tile's 8 loads, leave next
// tile's 7 mid-phase loads in flight (never drains to 0 in steady state).
// =====================================================================

#define PHASE_COMPUTE(q)                                                       \
  {                                                                            \
    bf16x8 af[2][2];                                                           \
    _Pragma("unroll") for (int mi = 0; mi < 2; ++mi)                           \
      _Pragma("unroll") for (int ks = 0; ks < 2; ++ks)                         \
        af[mi][ks] = *(const bf16x8*)((const char*)sAc +                       \
                       SWZ(wm * 128 + (q) * 32 + mi * 16 + m,                  \
                           ks * 64 + g * 16));                                 \
    __builtin_amdgcn_s_setprio(1);                                             \
    _Pragma("unroll") for (int mi = 0; mi < 2; ++mi)                           \
      _Pragma("unroll") for (int ni = 0; ni < 4; ++ni) {                       \
        acc[(q) * 2 + mi][ni] = __builtin_amdgcn_mfma_f32_16x16x32_bf16(       \
            af[mi][0], bfr[ni][0], acc[(q) * 2 + mi][ni], 0, 0, 0);            \
        acc[(q) * 2 + mi][ni] = __builtin_amdgcn_mfma_f32_16x16x32_bf16(       \
            af[mi][1], bfr[ni][1], acc[(q) * 2 + mi][ni], 0, 0, 0);            \
      }                                                                        \
    __builtin_amdgcn_s_setprio(0);                                             \
  }

#define GEMM256_8PH(A_, lda_, B_, ldb_, K_)                                    \
  __shared__ unsigned short sA[2][256 * 64];                                   \
  __shared__ unsigned short sB[2][256 * 64];                                   \
  int id = blockIdx.x;                                                         \
  int swz = (id & 7) * cpx + (id >> 3);                                        \
  int m0 = (swz / NB) * 256, n0 = (swz % NB) * 256;                            \
  int tid = threadIdx.x, lane = tid & 63;                                      \
  int wid = tid >> 6, wm = wid >> 2, wn = wid & 3;                             \
  int m = lane & 15, g = lane >> 4;                                            \
  int r5 = tid >> 3;                              /* 0..63 */                  \
  int ce = ((((tid & 7) * 16) ^ ((r5 & 7) << 4)) >> 1); /* pre-swz col elem */ \
  int lde = (tid & 7) * 8;                        /* linear LDS col elem  */   \
  int rowA[4], rowB[4];                                                        \
  _Pragma("unroll") for (int q = 0; q < 4; ++q) {                              \
    rowA[q] = (r5 < 32) ? (q * 32 + r5) : (96 + q * 32 + r5);                  \
    rowB[q] = q * 64 + r5;                                                     \
  }                                                                            \
  const unsigned short* aSrc[4];                                               \
  const unsigned short* bSrc[4];                                               \
  int aOff[4], bOff[4];                                                        \
  _Pragma("unroll") for (int q = 0; q < 4; ++q) {                              \
    aSrc[q] = (A_) + (size_t)(m0 + rowA[q]) * (lda_) + ce;                     \
    bSrc[q] = (B_) + (size_t)(n0 + rowB[q]) * (ldb_) + ce;                     \
    aOff[q] = rowA[q] * 64 + lde;                                              \
    bOff[q] = rowB[q] * 64 + lde;                                              \
  }                                                                            \
  f32x4 acc[8][4] = {};                                                        \
  int nt = (K_) >> 6;                                                          \
  /* prologue: tile0 all 8, tile1 first 7 (A-s3(1) issued at kt=0 ph0) */      \
  _Pragma("unroll") for (int q = 0; q < 4; ++q) {                              \
    gll16(bSrc[q], &sB[0][bOff[q]]);                                           \
    gll16(aSrc[q], &sA[0][aOff[q]]);                                           \
  }                                                                            \
  _Pragma("unroll") for (int q = 0; q < 4; ++q)                                \
    gll16(bSrc[q] + 64, &sB[1][bOff[q]]);                                      \
  _Pragma("unroll") for (int q = 0; q < 3; ++q)                                \
    gll16(aSrc[q] + 64, &sA[1][aOff[q]]);                                      \
  for (int kt = 0; kt < nt; ++kt) {                                            \
    int cur = kt & 1;                                                          \
    const unsigned short* sAc = sA[cur];                                       \
    const unsigned short* sBc = sB[cur];                                       \
    /* ---- phase 0: wait own tile, finish next tile's A-s3, B+q0 ---- */      \
    if (kt + 1 < nt) {                                                         \
      asm volatile("s_waitcnt vmcnt(7)" ::: "memory");                         \
      gll16(aSrc[3] + (kt + 1) * 64, &sA[cur ^ 1][aOff[3]]);                   \
    } else {                                                                   \
      asm volatile("s_waitcnt vmcnt(0)" ::: "memory");                         \
    }                                                                          \
    asm volatile("s_barrier" ::: "memory");                                    \
    bf16x8 bfr[4][2];                                                          \
    _Pragma("unroll") for (int ni = 0; ni < 4; ++ni)                           \
      _Pragma("unroll") for (int ks = 0; ks < 2; ++ks)                         \
        bfr[ni][ks] = *(const bf16x8*)((const char*)sBc +                      \
                        SWZ(wn * 64 + ni * 16 + m, ks * 64 + g * 16));         \
    PHASE_COMPUTE(0)                                                           \
    asm volatile("s_barrier" ::: "memory");                                    \
    /* ---- phase 1: B[cur] dead -> stage B-h0(kt+2) ---- */                   \
    if (kt + 2 < nt) {                                                         \
      int ko = (kt + 2) * 64;                                                  \
      gll16(bSrc[0] + ko, &sB[cur][bOff[0]]);                                  \
      gll16(bSrc[1] + ko, &sB[cur][bOff[1]]);                                  \
    }                                                                          \
    PHASE_COMPUTE(1)                                                           \
    asm volatile("s_barrier" ::: "memory");                                    \
    /* ---- phase 2: stage B-h1 + A-s0 (dead after ph0) ---- */                \
    if (kt + 2 < nt) {                                                         \
      int ko = (kt + 2) * 64;                                                  \
      gll16(bSrc[2] + ko, &sB[cur][bOff[2]]);                                  \
      gll16(bSrc[3] + ko, &sB[cur][bOff[3]]);                                  \
      gll16(aSrc[0] + ko, &sA[cur][aOff[0]]);                                  \
    }                                                                          \
    PHASE_COMPUTE(2)                                                           \
    asm volatile("s_barrier" ::: "memory");                                    \
    /* ---- phase 3: stage A-s1 (dead ph1) + A-s2 (dead ph2) ---- */           \
    if (kt + 2 < nt) {                                                         \
      int ko = (kt + 2) * 64;                                                  \
      gll16(aSrc[1] + ko, &sA[cur][aOff[1]]);                                  \
      gll16(aSrc[2] + ko, &sA[cur][aOff[2]]);                                  \
    }                                                                          \
    PHASE_COMPUTE(3)                                                           \
    asm volatile("s_barrier" ::: "memory");                                    \
  }

// ---------------- GEMM1 (half-H): act = gelu(A @ Bw^T + bias), bf16 out ----
__global__ __launch_bounds__(512, 2) void gemm_gelu_kernel(
    const unsigned short* __restrict__ A, int lda,
    const unsigned short* __restrict__ Bw, int ldb,
    const float* __restrict__ bias, unsigned short* __restrict__ Out, int ldo,
    int K, int NB, int cpx)
{
  GEMM256_8PH(A, lda, Bw, ldb, K)

#pragma unroll
  for (int mi = 0; mi < 8; ++mi) {
    int row = m0 + wm * 128 + mi * 16 + g * 4;
#pragma unroll
    for (int ni = 0; ni < 4; ++ni) {
      int col = n0 + wn * 64 + ni * 16 + m;
      float bcol = bias[col];
#pragma unroll
      for (int r = 0; r < 4; ++r) {
        float v = acc[mi][ni][r] + bcol;
        v = 0.5f * v * (1.f + erff(v * 0.70710678118f));
        Out[(size_t)(row + r) * ldo + col] = f2bf(v);
      }
    }
  }
}

// ---------------- GEMM2 (half-K pass): Out = acc (+bias) + add -------------
__global__ __launch_bounds__(512, 2) void gemm_acc_kernel(
    const unsigned short* __restrict__ A, int lda,
    const unsigned short* __restrict__ Bw, int ldb,
    const float* __restrict__ bias,       // may be null
    const float* add, float* Out, int K, int NB, int cpx)
{
  GEMM256_8PH(A, lda, Bw, ldb, K)

#pragma unroll
  for (int mi = 0; mi < 8; ++mi) {
    int row = m0 + wm * 128 + mi * 16 + g * 4;
#pragma unroll
    for (int ni = 0; ni < 4; ++ni) {
      int col = n0 + wn * 64 + ni * 16 + m;
      float bcol = bias ? bias[col] : 0.f;
#pragma unroll
      for (int r = 0; r < 4; ++r) {
        size_t off = (size_t)(row + r) * CC + col;
        Out[off] = acc[mi][ni][r] + bcol + add[off];
      }
    }
  }
}

// ---------------- launch ----------------
extern "C" void kernel_launch(void* const* d_in, const int* in_sizes, int n_in,
                              void* d_out, int out_size, void* d_ws, size_t ws_size,
                              hipStream_t stream)
{
  const float* x       = (const float*)d_in[0];
  const float* log_tau = (const float*)d_in[1];
  const float* log_dt  = (const float*)d_in[2];
  const float* mix     = (const float*)d_in[3];
  const float* Dv      = (const float*)d_in[4];
  const float* n1w     = (const float*)d_in[5];
  const float* n1b     = (const float*)d_in[6];
  const float* n2w     = (const float*)d_in[7];
  const float* n2b     = (const float*)d_in[8];
  const float* w1      = (const float*)d_in[9];
  const float* b1      = (const float*)d_in[10];
  const float* w2      = (const float*)d_in[11];
  const float* b2      = (const float*)d_in[12];

  // workspace layout (176 MB total)
  char* ws = (char*)d_ws;
  float* buf0 = (float*)ws;
  float* buf1 = (float*)(ws + (64ull << 20));
  unsigned short* a2  = (unsigned short*)(ws + (128ull << 20));
  unsigned short* w1b = (unsigned short*)(ws + (160ull << 20));
  unsigned short* w2b = (unsigned short*)(ws + (168ull << 20));
  unsigned short* act = (unsigned short*)buf0;   // alias: M x 2048 bf16 = 64 MB
  float* out = (float*)d_out;

  // 1. h = LN1(x)
  ln_f32_kernel<<<MM, 256, 0, stream>>>(x, n1w, n1b, buf0);
  // 2. hT = transpose(h)
  transpose_kernel<<<dim3(CC / 64, TT / 64, BB), 256, 0, stream>>>(buf0, buf1);
  // 3. y = s4d(hT)   (y -> buf0)
  s4d_kernel<<<BB * CC, 256, 0, stream>>>(buf1, log_tau, log_dt, mix, Dv, buf0);
  // 4. x2 = x + y^T  (x2 -> buf1)
  transadd_kernel<<<dim3(TT / 64, CC / 64, BB), 256, 0, stream>>>(buf0, x, buf1);
  // 5. a2 = bf16(LN2(x2))   (buf0/y now dead -> act aliases it)
  ln_bf16_kernel<<<MM, 256, 0, stream>>>(buf1, n2w, n2b, a2);
  // 6. weight casts
  cvt_bf16_kernel<<<(HH * CC / 4) / 256, 256, 0, stream>>>(w1, w1b);
  cvt_bf16_kernel<<<(HH * CC / 4) / 256, 256, 0, stream>>>(w2, w2b);

  // 7/8. MLP split along H into two halves of 2048 (act buffer = 64 MB)
  // gemm_gelu: grid 64x8=512, NB=8, cpx=64, K=1024
  // gemm_acc:  grid 64x4=256, NB=4, cpx=32, K=2048
  // half 0
  gemm_gelu_kernel<<<512, 512, 0, stream>>>(
      a2, CC, w1b, CC, b1, act, 2048, CC, 8, 64);
  gemm_acc_kernel<<<256, 512, 0, stream>>>(
      act, 2048, w2b, HH, b2, buf1, out, 2048, 4, 32);
  // half 1
  gemm_gelu_kernel<<<512, 512, 0, stream>>>(
      a2, CC, w1b + (size_t)2048 * CC, CC, b1 + 2048, act, 2048, CC, 8, 64);
  gemm_acc_kernel<<<256, 512, 0, stream>>>(
      act, 2048, w2b + 2048, HH, (const float*)nullptr, out, out, 2048, 4, 32);
}